// Round 8
// baseline (239.561 us; speedup 1.0000x reference)
//
#include <hip/hip_runtime.h>

#define NNODES 100000
#define NEDGES 3200000
#define ETOT   (NEDGES + NNODES)
#define NEG_SLOPE 0.2f
#define LOG2E 1.4426950408889634f

#define NPB 64                               // nodes per bucket (dst >> 6)
#define NBUCK ((NNODES + NPB - 1) / NPB)     // 1563 buckets
#define NCHUNK 256                           // edge chunks
#define CHUNK_E ((ETOT + NCHUNK - 1) / NCHUNK)  // 12891 edges/chunk
#define M2 (NBUCK * NCHUNK)                  // 400128 (chunk-scan length)
#define NSB2 ((M2 + 511) / 512)              // 782

// bf16 storage via raw ushort — no hip_fp16.h / hip_bf16.h dependency.
__device__ __forceinline__ unsigned short f2bf(float f) {
    unsigned u = __float_as_uint(f);
    u += 0x7FFFu + ((u >> 16) & 1u);         // round-to-nearest-even
    return (unsigned short)(u >> 16);
}
__device__ __forceinline__ float bf2f(unsigned short h) {
    return __uint_as_float(((unsigned)h) << 16);
}

// edge e in [0, NEDGES): src = ei[e], dst = ei[NEDGES+e]
// edge e in [NEDGES, ETOT): self-loop, src = dst = e - NEDGES
__device__ __forceinline__ void edge_sd(int e, const int* __restrict__ ei, int& s, int& d) {
    if (e < NEDGES) { s = ei[e]; d = ei[NEDGES + e]; }
    else            { s = e - NEDGES; d = s; }
}

__device__ __forceinline__ float lrelu(float v) {
    return v > 0.0f ? v : NEG_SLOPE * v;
}

// Round-26: alpha tables are pre-scaled by log2(e) (lrelu commutes with
// positive scale), so the per-edge weight is a single v_exp_f32 (2^x), no mul.
__device__ __forceinline__ float edge_w(float z) {
    return __builtin_amdgcn_exp2f(lrelu(z));
}

// Broadcast from a compile-time lane: v_readlane -> SGPR (scalar pipe, no DS op).
__device__ __forceinline__ float bcast_lane(float v, int lane_imm) {
    return __int_as_float(__builtin_amdgcn_readlane(__float_as_int(v), lane_imm));
}

// ---- cross-lane primitives ----
template<int CTRL>
__device__ __forceinline__ float dpp_mov(float v) {
    return __int_as_float(__builtin_amdgcn_mov_dpp(__float_as_int(v), CTRL, 0xF, 0xF, true));
}
template<int CTRL>
__device__ __forceinline__ float dpp_add(float v) { return v + dpp_mov<CTRL>(v); }
template<int IMM>
__device__ __forceinline__ float swz(float v) {
    return __int_as_float(__builtin_amdgcn_ds_swizzle(__float_as_int(v), IMM));
}
// Cross-row within a 32-lane half: ds_swizzle xor-16.
__device__ __forceinline__ float swz16_add(float v) { return v + swz<0x401F>(v); }
// Sum over all 16 lanes of each row (rotations 1,2,4,8).
__device__ __forceinline__ float row16_sum(float v) {
    v = dpp_add<0x121>(v);   // row_ror:1
    v = dpp_add<0x122>(v);   // row_ror:2
    v = dpp_add<0x124>(v);   // row_ror:4
    v = dpp_add<0x128>(v);   // row_ror:8
    return v;
}
// Full 64-lane sum; every lane ends with the total.
__device__ __forceinline__ float wave64_sum(float v) {
    v = row16_sum(v);
    v = swz16_add(v);
    v += __shfl_xor(v, 32);
    return v;
}

// ---------------- deterministic chunked bucket sort ----------------

__global__ void chunk_hist(const int* __restrict__ ei, int* __restrict__ H) {
    __shared__ int h[NBUCK];
    int c = blockIdx.x;
    for (int i = threadIdx.x; i < NBUCK; i += blockDim.x) h[i] = 0;
    __syncthreads();
    int lo = c * CHUNK_E, hi = lo + CHUNK_E; if (hi > ETOT) hi = ETOT;
    for (int e = lo + threadIdx.x; e < hi; e += blockDim.x) {
        int d = (e < NEDGES) ? ei[NEDGES + e] : (e - NEDGES);
        atomicAdd(&h[d >> 6], 1);
    }
    __syncthreads();
    for (int i = threadIdx.x; i < NBUCK; i += blockDim.x) H[c * NBUCK + i] = h[i];
}

// 3-phase exclusive scan of H in bucket-major order.
// Linear index i = b*NCHUNK + c (NCHUNK=256: b = i>>8, c = i&255); value = H[c*NBUCK+b].
__global__ void cscan_local(const int* __restrict__ H, int* __restrict__ off,
                            int* __restrict__ bsum2) {
    __shared__ int arr[512];
    int blk = blockIdx.x, t = threadIdx.x;
    int i = blk * 512 + t;
    int v = (i < M2) ? H[(i & (NCHUNK - 1)) * NBUCK + (i >> 8)] : 0;
    arr[t] = v;
    __syncthreads();
    for (int o = 1; o < 512; o <<= 1) {
        int u = (t >= o) ? arr[t - o] : 0;
        __syncthreads();
        arr[t] += u;
        __syncthreads();
    }
    if (i < M2) off[i] = arr[t] - v;
    if (t == 511) bsum2[blk] = arr[t];
}

__global__ void cscan_bsum(const int* __restrict__ bsum2, int* __restrict__ boff2) {
    __shared__ int arr[1024];
    int t = threadIdx.x;
    int v = (t < NSB2) ? bsum2[t] : 0;
    arr[t] = v;
    __syncthreads();
    for (int o = 1; o < 1024; o <<= 1) {
        int u = (t >= o) ? arr[t - o] : 0;
        __syncthreads();
        arr[t] += u;
        __syncthreads();
    }
    if (t < NSB2) boff2[t] = arr[t] - v;
}

__global__ void cscan_add(int* __restrict__ off, const int* __restrict__ boff2) {
    int i = blockIdx.x * 512 + threadIdx.x;
    if (i < M2) off[i] += boff2[blockIdx.x];
}

// LDS-staged scatter (round-22, proven: WRITE_SIZE 67-78MB -> off top-5).
__global__ __launch_bounds__(1024)
void chunk_scatter(const int* __restrict__ ei, const int* __restrict__ off,
                   const int* __restrict__ H, int* __restrict__ pairs) {
    __shared__ int plds[CHUNK_E];            // 51564 B: packed pair per local slot
    __shared__ unsigned short blds[CHUNK_E]; // 25782 B: bucket id per local slot
    __shared__ int sc[2048];                 //  8192 B: inclusive scan of counts
    __shared__ int lcur[NBUCK];              //  6252 B: local alloc cursor
    __shared__ int gbase[NBUCK];             //  6252 B: off[b,c] - lpref[b]
    int c = blockIdx.x, t = threadIdx.x;
    for (int b = t; b < 2048; b += 1024) sc[b] = (b < NBUCK) ? H[c * NBUCK + b] : 0;
    __syncthreads();
    for (int o = 1; o < 2048; o <<= 1) {
        int i1 = t + 1024;
        int v0 = (t >= o) ? sc[t - o] : 0;
        int v1 = (i1 >= o) ? sc[i1 - o] : 0;
        __syncthreads();
        sc[t] += v0; sc[i1] += v1;
        __syncthreads();
    }
    for (int b = t; b < NBUCK; b += 1024) {
        int excl = (b == 0) ? 0 : sc[b - 1];        // exclusive local prefix
        lcur[b]  = excl;
        gbase[b] = off[b * NCHUNK + c] - excl;
    }
    __syncthreads();
    int lo = c * CHUNK_E, hi = lo + CHUNK_E; if (hi > ETOT) hi = ETOT;
    int n = hi - lo;
    for (int e = lo + t; e < hi; e += 1024) {
        int s, d; edge_sd(e, ei, s, d);
        int b = d >> 6;
        int slot = atomicAdd(&lcur[b], 1);
        plds[slot] = ((d & 63) << 17) | s;          // src < 2^17
        blds[slot] = (unsigned short)b;
    }
    __syncthreads();
    for (int i = t; i < n; i += 1024)
        pairs[gbase[blds[i]] + i] = plds[i];        // coalesced within segments
}

__global__ void fine_sort2(const int* __restrict__ off, const int* __restrict__ pairs,
                           int* __restrict__ row_start, int* __restrict__ csr_src) {
    __shared__ int arr[NPB];
    __shared__ int cur[NPB];
    int b = blockIdx.x;
    int t = threadIdx.x;
    int base = off[b * NCHUNK];
    int bend = (b == NBUCK - 1) ? ETOT : off[(b + 1) * NCHUNK];
    if (t < NPB) arr[t] = 0;
    __syncthreads();
    for (int i = base + t; i < bend; i += blockDim.x)
        atomicAdd(&arr[pairs[i] >> 17], 1);
    __syncthreads();
    int v = (t < NPB) ? arr[t] : 0;
    __syncthreads();
    for (int o = 1; o < NPB; o <<= 1) {           // inclusive scan over 64 counts
        int u = (t < NPB && t >= o) ? arr[t - o] : 0;
        __syncthreads();
        if (t < NPB) arr[t] += u;
        __syncthreads();
    }
    if (t < NPB) {
        int node = b * NPB + t;
        int start = base + arr[t] - v;            // exclusive prefix
        cur[t] = start;
        if (node < NNODES) row_start[node] = start;
    }
    if (b == NBUCK - 1 && t == 0) row_start[NNODES] = ETOT;
    __syncthreads();
    for (int i = base + t; i < bend; i += blockDim.x) {
        int p = pairs[i];
        int slot = atomicAdd(&cur[p >> 17], 1);
        csr_src[slot] = p & 0x1FFFF;
    }
}

// ---------------- attention-vector precompute ----------------
// cvec layout: [0,1]=c1s  [2,3]=c1d  [4..19]=c2s  [20..35]=c2d
// Round-26: all entries pre-scaled by log2(e) so edge weights use raw 2^x.
__global__ void prep(const float* __restrict__ W1, const float* __restrict__ as1,
                     const float* __restrict__ ad1, const float* __restrict__ W2,
                     const float* __restrict__ as2, const float* __restrict__ ad2,
                     float* __restrict__ cvec) {
    int t = threadIdx.x;
    if (t < 2) {
        float s = 0.f, d = 0.f;
        for (int f = 0; f < 16; ++f) { s += W1[t * 16 + f] * as1[f]; d += W1[t * 16 + f] * ad1[f]; }
        cvec[t] = s * LOG2E; cvec[2 + t] = d * LOG2E;
    }
    if (t < 16) {
        float s = 0.f, d = 0.f;
        for (int f = 0; f < 64; ++f) { s += W2[t * 64 + f] * as2[f]; d += W2[t * 64 + f] * ad2[f]; }
        cvec[4 + t] = s * LOG2E; cvec[20 + t] = d * LOG2E;
    }
}

__global__ void alpha1(const float* __restrict__ x, const float* __restrict__ cvec,
                       float* __restrict__ as_, float* __restrict__ ad_) {
    int n = blockIdx.x * blockDim.x + threadIdx.x;
    if (n >= NNODES) return;
    float2 xv = ((const float2*)x)[n];
    as_[n] = xv.x * cvec[0] + xv.y * cvec[1];
    ad_[n] = xv.x * cvec[2] + xv.y * cvec[3];
}

// ---------------- layer 1: aggregate x (2 feats), @W1 in epilogue -------------
// One edge per lane (stride 64); DPP/swz reduction; alpha2 fused in epilogue.
// Zero LDS, zero barriers; 256-thread blocks. Round-26: manual prefetch
// removed (it double-issued every gather in the common deg<=64 one-iteration
// case); plain loop like agg_l2. Edge weight = single v_exp_f32.
__global__ void agg_l1(const int* __restrict__ row_start, const int* __restrict__ csr_src,
                       const float* __restrict__ as_, const float* __restrict__ ad_,
                       const float* __restrict__ x, const float* __restrict__ W1,
                       const float* __restrict__ b1, const float* __restrict__ cvec,
                       unsigned short* __restrict__ g,
                       float* __restrict__ as2_, float* __restrict__ ad2_) {
    int wave = threadIdx.x >> 6, lane = threadIdx.x & 63;
    int node = blockIdx.x * 4 + wave;          // always < NNODES (exact grid)
    int base = row_start[node], end = row_start[node + 1];
    float adv = ad_[node];
    float a0 = 0.f, a1 = 0.f, ss = 0.f;
    const float2* x2 = (const float2*)x;
    for (int i = base + lane; i < end; i += 64) {
        int sj = csr_src[i];
        float w = edge_w(as_[sj] + adv);
        float2 xv = x2[sj];
        ss += w;
        a0 += w * xv.x;
        a1 += w * xv.y;
    }
    a0 = wave64_sum(a0); a1 = wave64_sum(a1); ss = wave64_sum(ss);
    int f = lane & 15;                         // all lanes compute feature f
    float v = (a0 * W1[f] + a1 * W1[16 + f]) / ss + b1[f];
    float vr = v > 0.f ? v : 0.f;
    if (lane < 16) g[node * 16 + lane] = f2bf(vr);
    // fused alpha2 (f32, log2e-prescaled cvec): row-local 16-feature sums
    float s2 = vr * cvec[4 + f];
    float d2 = vr * cvec[20 + f];
    s2 = row16_sum(s2); d2 = row16_sum(d2);
    if (lane == 0) { as2_[node] = s2; ad2_[node] = d2; }
}

// ---------------- layer 2: aggregate bf16 g, @W2 in epilogue ------------------
// One edge per lane, full 32B g-row per lane (round-24); transposed butterfly
// reduce (round-25): lane l ends with the total of feature l&15; readlane
// broadcasts feed the W2 matvec. Round-26: edge weight = single v_exp_f32
// (exp accounted for ~60% of VALU-busy at 4cy wave64; the feeding v_mul is
// folded into the prescaled alpha tables).
__global__ void agg_l2(const int* __restrict__ row_start, const int* __restrict__ csr_src,
                       const float* __restrict__ as_, const float* __restrict__ ad_,
                       const unsigned short* __restrict__ g, const float* __restrict__ W2,
                       const float* __restrict__ b2, float* __restrict__ out) {
    int wave = threadIdx.x >> 6, lane = threadIdx.x & 63;
    int node = blockIdx.x * 4 + wave; // always < NNODES (exact grid)
    int base = row_start[node], end = row_start[node + 1];
    float adv = ad_[node];
    float acc[16];
#pragma unroll
    for (int k = 0; k < 16; ++k) acc[k] = 0.f;
    float ss = 0.f;
    for (int i = base + lane; i < end; i += 64) {   // one iteration for deg<=64
        int sj = csr_src[i];                        // coalesced (consecutive i)
        float w = edge_w(as_[sj] + adv);
        ss += w;
        const uint4* gp = (const uint4*)(g + sj * 16);  // row 32B-aligned
        uint4 u0 = gp[0], u1 = gp[1];                   // full row, 2 insts
        unsigned uu[8] = {u0.x, u0.y, u0.z, u0.w, u1.x, u1.y, u1.z, u1.w};
#pragma unroll
        for (int j = 0; j < 8; ++j) {
            acc[2 * j]     += w * __uint_as_float(uu[j] << 16);
            acc[2 * j + 1] += w * __uint_as_float(uu[j] & 0xFFFF0000u);
        }
    }
    // ---- transposed butterfly reduce: lane l ends with total of feature l&15
    // stage bit0: partner l^1 (quad_perm [1,0,3,2] = 0xB1)
#pragma unroll
    for (int j = 0; j < 8; ++j) {
        float keep = (lane & 1) ? acc[2 * j + 1] : acc[2 * j];
        float send = (lane & 1) ? acc[2 * j]     : acc[2 * j + 1];
        acc[j] = keep + dpp_mov<0xB1>(send);
    }
    // stage bit1: partner l^2 (quad_perm [2,3,0,1] = 0x4E)
#pragma unroll
    for (int j = 0; j < 4; ++j) {
        float keep = (lane & 2) ? acc[2 * j + 1] : acc[2 * j];
        float send = (lane & 2) ? acc[2 * j]     : acc[2 * j + 1];
        acc[j] = keep + dpp_mov<0x4E>(send);
    }
    // stage bit2: partner l^4 (ds_swizzle xor4)
#pragma unroll
    for (int j = 0; j < 2; ++j) {
        float keep = (lane & 4) ? acc[2 * j + 1] : acc[2 * j];
        float send = (lane & 4) ? acc[2 * j]     : acc[2 * j + 1];
        acc[j] = keep + swz<0x101F>(send);
    }
    // stage bit3: partner l^8 (ds_swizzle xor8)
    float r;
    {
        float keep = (lane & 8) ? acc[1] : acc[0];
        float send = (lane & 8) ? acc[0] : acc[1];
        r = keep + swz<0x201F>(send);
    }
    // cross-row: xor16 + xor32 -> full-wave total of feature lane&15
    r = swz16_add(r);
    r += __shfl_xor(r, 32);
    float st = wave64_sum(ss);
    // Feature k total lives in lane k (k=0..15): readlane + coalesced W2 column.
    float o = 0.f;
#pragma unroll
    for (int k = 0; k < 16; ++k)
        o += bcast_lane(r, k) * W2[k * 64 + lane];
    o = o / st + b2[lane];                         // single normalize per node
    out[(size_t)node * 64 + lane] = o > 0.f ? o : 0.f;
}

extern "C" void kernel_launch(void* const* d_in, const int* in_sizes, int n_in,
                              void* d_out, int out_size, void* d_ws, size_t ws_size,
                              hipStream_t stream) {
    const float* x     = (const float*)d_in[0];
    const int*   ei    = (const int*)  d_in[1];
    const float* W1    = (const float*)d_in[2];
    const float* as1w  = (const float*)d_in[3];
    const float* ad1w  = (const float*)d_in[4];
    const float* b1    = (const float*)d_in[5];
    const float* W2    = (const float*)d_in[6];
    const float* as2w  = (const float*)d_in[7];
    const float* ad2w  = (const float*)d_in[8];
    const float* b2    = (const float*)d_in[9];
    float* out = (float*)d_out;

    // ws layout (4-byte elems, ~37 MB; 40.4 MB proven available):
    //   row_start[N+4] | csr_src[ETOT] | g[N*16 bf16, in former float slot] |
    //   asb[N] | adb[N] | as2b[N] | ad2b[N] | cvec[64] | pairs[ETOT] |
    //   H[M2] | off[M2] | bsum2[1024] | boff2[1024]
    int* row_start = (int*)d_ws;
    int* csr_src   = row_start + (NNODES + 4);
    float* gslot   = (float*)(csr_src + ETOT);   // N*16 floats reserved
    unsigned short* gbuf = (unsigned short*)gslot;  // N*16 bf16 used
    float* asb     = gslot + (size_t)NNODES * 16;
    float* adb     = asb + NNODES;
    float* as2b    = adb + NNODES;
    float* ad2b    = as2b + NNODES;
    float* cvec    = ad2b + NNODES;              // 36 floats used
    int* pairs     = (int*)(cvec + 64);          // ETOT
    int* H         = pairs + ETOT;               // M2
    int* off       = H + M2;                     // M2
    int* bsum2     = off + M2;                   // 1024
    int* boff2     = bsum2 + 1024;               // 1024

    const int B = 256;
    const int NB = (NNODES + B - 1) / B;

    // ---- CSR build: deterministic chunked bucket sort ----
    chunk_hist<<<NCHUNK, 1024, 0, stream>>>(ei, H);
    cscan_local<<<NSB2, 512, 0, stream>>>(H, off, bsum2);
    cscan_bsum<<<1, 1024, 0, stream>>>(bsum2, boff2);
    cscan_add<<<NSB2, 512, 0, stream>>>(off, boff2);
    chunk_scatter<<<NCHUNK, 1024, 0, stream>>>(ei, off, H, pairs);
    fine_sort2<<<NBUCK, B, 0, stream>>>(off, pairs, row_start, csr_src);

    // ---- attention precompute ----
    prep<<<1, 64, 0, stream>>>(W1, as1w, ad1w, W2, as2w, ad2w, cvec);

    // ---- Layer 1: alphas from x, aggregate x, W1 in epilogue (g stored bf16);
    //      layer-2 alphas fused into the epilogue (alpha2 kernel eliminated) ----
    alpha1<<<NB, B, 0, stream>>>(x, cvec, asb, adb);
    agg_l1<<<NNODES / 4, B, 0, stream>>>(row_start, csr_src, asb, adb, x, W1, b1,
                                         cvec, gbuf, as2b, ad2b);

    // ---- Layer 2: aggregate bf16 g, W2 in epilogue ----
    agg_l2<<<NNODES / 4, B, 0, stream>>>(row_start, csr_src, as2b, ad2b, gbuf, W2, b2, out);
}

// Round 9
// 231.353 us; speedup vs baseline: 1.0355x; 1.0355x over previous
//
#include <hip/hip_runtime.h>

#define NNODES 100000
#define NEDGES 3200000
#define ETOT   (NEDGES + NNODES)
#define NEG_SLOPE 0.2f
#define LOG2E 1.4426950408889634f

#define NPB 64                               // nodes per bucket (dst >> 6)
#define NBUCK ((NNODES + NPB - 1) / NPB)     // 1563 buckets
#define NCHUNK 256                           // edge chunks
#define CHUNK_E ((ETOT + NCHUNK - 1) / NCHUNK)  // 12891 edges/chunk
#define M2 (NBUCK * NCHUNK)                  // 400128 (chunk-scan length)
#define NSB2 ((M2 + 511) / 512)              // 782

// bf16 storage via raw ushort — no hip_fp16.h / hip_bf16.h dependency.
__device__ __forceinline__ unsigned short f2bf(float f) {
    unsigned u = __float_as_uint(f);
    u += 0x7FFFu + ((u >> 16) & 1u);         // round-to-nearest-even
    return (unsigned short)(u >> 16);
}
__device__ __forceinline__ float bf2f(unsigned short h) {
    return __uint_as_float(((unsigned)h) << 16);
}

// edge e in [0, NEDGES): src = ei[e], dst = ei[NEDGES+e]
// edge e in [NEDGES, ETOT): self-loop, src = dst = e - NEDGES
__device__ __forceinline__ void edge_sd(int e, const int* __restrict__ ei, int& s, int& d) {
    if (e < NEDGES) { s = ei[e]; d = ei[NEDGES + e]; }
    else            { s = e - NEDGES; d = s; }
}

__device__ __forceinline__ float lrelu(float v) {
    return v > 0.0f ? v : NEG_SLOPE * v;
}

// Alpha tables pre-scaled by log2(e) (round-26): edge weight = single v_exp_f32.
__device__ __forceinline__ float edge_w(float z) {
    return __builtin_amdgcn_exp2f(lrelu(z));
}

// Broadcast from a compile-time lane: v_readlane -> SGPR (scalar pipe, no DS op).
__device__ __forceinline__ float bcast_lane(float v, int lane_imm) {
    return __int_as_float(__builtin_amdgcn_readlane(__float_as_int(v), lane_imm));
}

// ---- cross-lane primitives ----
template<int CTRL>
__device__ __forceinline__ float dpp_mov(float v) {
    return __int_as_float(__builtin_amdgcn_mov_dpp(__float_as_int(v), CTRL, 0xF, 0xF, true));
}
template<int CTRL>
__device__ __forceinline__ float dpp_add(float v) { return v + dpp_mov<CTRL>(v); }
template<int IMM>
__device__ __forceinline__ float swz(float v) {
    return __int_as_float(__builtin_amdgcn_ds_swizzle(__float_as_int(v), IMM));
}
// Cross-row within a 32-lane half: ds_swizzle xor-16.
__device__ __forceinline__ float swz16_add(float v) { return v + swz<0x401F>(v); }
// Sum over all 16 lanes of each row (rotations 1,2,4,8).
__device__ __forceinline__ float row16_sum(float v) {
    v = dpp_add<0x121>(v);   // row_ror:1
    v = dpp_add<0x122>(v);   // row_ror:2
    v = dpp_add<0x124>(v);   // row_ror:4
    v = dpp_add<0x128>(v);   // row_ror:8
    return v;
}
// Full 64-lane sum; every lane ends with the total.
__device__ __forceinline__ float wave64_sum(float v) {
    v = row16_sum(v);
    v = swz16_add(v);
    v += __shfl_xor(v, 32);
    return v;
}

// ---------------- deterministic chunked bucket sort ----------------

__global__ void chunk_hist(const int* __restrict__ ei, int* __restrict__ H) {
    __shared__ int h[NBUCK];
    int c = blockIdx.x;
    for (int i = threadIdx.x; i < NBUCK; i += blockDim.x) h[i] = 0;
    __syncthreads();
    int lo = c * CHUNK_E, hi = lo + CHUNK_E; if (hi > ETOT) hi = ETOT;
    for (int e = lo + threadIdx.x; e < hi; e += blockDim.x) {
        int d = (e < NEDGES) ? ei[NEDGES + e] : (e - NEDGES);
        atomicAdd(&h[d >> 6], 1);
    }
    __syncthreads();
    for (int i = threadIdx.x; i < NBUCK; i += blockDim.x) H[c * NBUCK + i] = h[i];
}

// 3-phase exclusive scan of H in bucket-major order.
// Linear index i = b*NCHUNK + c (NCHUNK=256: b = i>>8, c = i&255); value = H[c*NBUCK+b].
__global__ void cscan_local(const int* __restrict__ H, int* __restrict__ off,
                            int* __restrict__ bsum2) {
    __shared__ int arr[512];
    int blk = blockIdx.x, t = threadIdx.x;
    int i = blk * 512 + t;
    int v = (i < M2) ? H[(i & (NCHUNK - 1)) * NBUCK + (i >> 8)] : 0;
    arr[t] = v;
    __syncthreads();
    for (int o = 1; o < 512; o <<= 1) {
        int u = (t >= o) ? arr[t - o] : 0;
        __syncthreads();
        arr[t] += u;
        __syncthreads();
    }
    if (i < M2) off[i] = arr[t] - v;
    if (t == 511) bsum2[blk] = arr[t];
}

__global__ void cscan_bsum(const int* __restrict__ bsum2, int* __restrict__ boff2) {
    __shared__ int arr[1024];
    int t = threadIdx.x;
    int v = (t < NSB2) ? bsum2[t] : 0;
    arr[t] = v;
    __syncthreads();
    for (int o = 1; o < 1024; o <<= 1) {
        int u = (t >= o) ? arr[t - o] : 0;
        __syncthreads();
        arr[t] += u;
        __syncthreads();
    }
    if (t < NSB2) boff2[t] = arr[t] - v;
}

__global__ void cscan_add(int* __restrict__ off, const int* __restrict__ boff2) {
    int i = blockIdx.x * 512 + threadIdx.x;
    if (i < M2) off[i] += boff2[blockIdx.x];
}

// LDS-staged scatter (round-22, proven: WRITE_SIZE 67-78MB -> off top-5).
__global__ __launch_bounds__(1024)
void chunk_scatter(const int* __restrict__ ei, const int* __restrict__ off,
                   const int* __restrict__ H, int* __restrict__ pairs) {
    __shared__ int plds[CHUNK_E];            // 51564 B: packed pair per local slot
    __shared__ unsigned short blds[CHUNK_E]; // 25782 B: bucket id per local slot
    __shared__ int sc[2048];                 //  8192 B: inclusive scan of counts
    __shared__ int lcur[NBUCK];              //  6252 B: local alloc cursor
    __shared__ int gbase[NBUCK];             //  6252 B: off[b,c] - lpref[b]
    int c = blockIdx.x, t = threadIdx.x;
    for (int b = t; b < 2048; b += 1024) sc[b] = (b < NBUCK) ? H[c * NBUCK + b] : 0;
    __syncthreads();
    for (int o = 1; o < 2048; o <<= 1) {
        int i1 = t + 1024;
        int v0 = (t >= o) ? sc[t - o] : 0;
        int v1 = (i1 >= o) ? sc[i1 - o] : 0;
        __syncthreads();
        sc[t] += v0; sc[i1] += v1;
        __syncthreads();
    }
    for (int b = t; b < NBUCK; b += 1024) {
        int excl = (b == 0) ? 0 : sc[b - 1];        // exclusive local prefix
        lcur[b]  = excl;
        gbase[b] = off[b * NCHUNK + c] - excl;
    }
    __syncthreads();
    int lo = c * CHUNK_E, hi = lo + CHUNK_E; if (hi > ETOT) hi = ETOT;
    int n = hi - lo;
    for (int e = lo + t; e < hi; e += 1024) {
        int s, d; edge_sd(e, ei, s, d);
        int b = d >> 6;
        int slot = atomicAdd(&lcur[b], 1);
        plds[slot] = ((d & 63) << 17) | s;          // src < 2^17
        blds[slot] = (unsigned short)b;
    }
    __syncthreads();
    for (int i = t; i < n; i += 1024)
        pairs[gbase[blds[i]] + i] = plds[i];        // coalesced within segments
}

__global__ void fine_sort2(const int* __restrict__ off, const int* __restrict__ pairs,
                           int* __restrict__ row_start, int* __restrict__ csr_src) {
    __shared__ int arr[NPB];
    __shared__ int cur[NPB];
    int b = blockIdx.x;
    int t = threadIdx.x;
    int base = off[b * NCHUNK];
    int bend = (b == NBUCK - 1) ? ETOT : off[(b + 1) * NCHUNK];
    if (t < NPB) arr[t] = 0;
    __syncthreads();
    for (int i = base + t; i < bend; i += blockDim.x)
        atomicAdd(&arr[pairs[i] >> 17], 1);
    __syncthreads();
    int v = (t < NPB) ? arr[t] : 0;
    __syncthreads();
    for (int o = 1; o < NPB; o <<= 1) {           // inclusive scan over 64 counts
        int u = (t < NPB && t >= o) ? arr[t - o] : 0;
        __syncthreads();
        if (t < NPB) arr[t] += u;
        __syncthreads();
    }
    if (t < NPB) {
        int node = b * NPB + t;
        int start = base + arr[t] - v;            // exclusive prefix
        cur[t] = start;
        if (node < NNODES) row_start[node] = start;
    }
    if (b == NBUCK - 1 && t == 0) row_start[NNODES] = ETOT;
    __syncthreads();
    for (int i = base + t; i < bend; i += blockDim.x) {
        int p = pairs[i];
        int slot = atomicAdd(&cur[p >> 17], 1);
        csr_src[slot] = p & 0x1FFFF;
    }
}

// ---------------- attention-vector precompute ----------------
// cvec layout: [0,1]=c1s  [2,3]=c1d  [4..19]=c2s  [20..35]=c2d (log2e-prescaled)
__global__ void prep(const float* __restrict__ W1, const float* __restrict__ as1,
                     const float* __restrict__ ad1, const float* __restrict__ W2,
                     const float* __restrict__ as2, const float* __restrict__ ad2,
                     float* __restrict__ cvec) {
    int t = threadIdx.x;
    if (t < 2) {
        float s = 0.f, d = 0.f;
        for (int f = 0; f < 16; ++f) { s += W1[t * 16 + f] * as1[f]; d += W1[t * 16 + f] * ad1[f]; }
        cvec[t] = s * LOG2E; cvec[2 + t] = d * LOG2E;
    }
    if (t < 16) {
        float s = 0.f, d = 0.f;
        for (int f = 0; f < 64; ++f) { s += W2[t * 64 + f] * as2[f]; d += W2[t * 64 + f] * ad2[f]; }
        cvec[4 + t] = s * LOG2E; cvec[20 + t] = d * LOG2E;
    }
}

// Round-27: layer-1 node record (16B, ONE cache line per edge gather):
// {x0, x1, as1, pad}. Previously each edge gathered as_[sj] AND x2[sj] from
// two tables = 2 divergent lines/edge. 4 rounds of VALU-side changes left
// agg duration pinned at ~54us while VALUBusy swung 52-72% -> the invariant
// cost is divergent-gather LINE traffic; this halves it.
__global__ void alpha1(const float* __restrict__ x, const float* __restrict__ cvec,
                       float4* __restrict__ nrec1, float* __restrict__ ad_) {
    int n = blockIdx.x * blockDim.x + threadIdx.x;
    if (n >= NNODES) return;
    float2 xv = ((const float2*)x)[n];
    float as = xv.x * cvec[0] + xv.y * cvec[1];
    ad_[n] = xv.x * cvec[2] + xv.y * cvec[3];
    nrec1[n] = make_float4(xv.x, xv.y, as, 0.f);
}

// ---------------- layer 1: aggregate x (2 feats), @W1 in epilogue -------------
// One edge per lane; single 16B record gather per edge; DPP/swz reduction;
// alpha2 fused in epilogue. Output: layer-2 node record (64B, one line):
// {g[16] bf16 (32B) | as2 f32 | pad} at nrec2 + node*64B.
__global__ void agg_l1(const int* __restrict__ row_start, const int* __restrict__ csr_src,
                       const float4* __restrict__ nrec1, const float* __restrict__ ad_,
                       const float* __restrict__ W1, const float* __restrict__ b1,
                       const float* __restrict__ cvec,
                       float* __restrict__ nrec2, float* __restrict__ ad2_) {
    int wave = threadIdx.x >> 6, lane = threadIdx.x & 63;
    int node = blockIdx.x * 4 + wave;          // always < NNODES (exact grid)
    int base = row_start[node], end = row_start[node + 1];
    float adv = ad_[node];
    float a0 = 0.f, a1 = 0.f, ss = 0.f;
    for (int i = base + lane; i < end; i += 64) {
        int sj = csr_src[i];
        float4 r = nrec1[sj];                  // ONE 16B gather: x0,x1,as1
        float w = edge_w(r.z + adv);
        ss += w;
        a0 += w * r.x;
        a1 += w * r.y;
    }
    a0 = wave64_sum(a0); a1 = wave64_sum(a1); ss = wave64_sum(ss);
    int f = lane & 15;                         // all lanes compute feature f
    float v = (a0 * W1[f] + a1 * W1[16 + f]) / ss + b1[f];
    float vr = v > 0.f ? v : 0.f;
    unsigned short* grow = (unsigned short*)(nrec2 + (size_t)node * 16);
    if (lane < 16) grow[lane] = f2bf(vr);      // bf16 g row, bytes 0..31
    // fused alpha2 (f32, log2e-prescaled cvec): row-local 16-feature sums
    float s2 = vr * cvec[4 + f];
    float d2 = vr * cvec[20 + f];
    s2 = row16_sum(s2); d2 = row16_sum(d2);
    if (lane == 0) {
        nrec2[(size_t)node * 16 + 8] = s2;     // as2 at bytes 32..35 (same line)
        ad2_[node] = d2;
    }
}

// ---------------- layer 2: aggregate bf16 g, @W2 in epilogue ------------------
// One edge per lane; the ENTIRE per-source payload (g row + as2) is one 64B
// record = one cache line per edge (was 2: g row + as2_ line). Transposed
// butterfly reduce (round-25); readlane broadcasts feed the W2 matvec.
__global__ void agg_l2(const int* __restrict__ row_start, const int* __restrict__ csr_src,
                       const float* __restrict__ nrec2, const float* __restrict__ ad_,
                       const float* __restrict__ W2, const float* __restrict__ b2,
                       float* __restrict__ out) {
    int wave = threadIdx.x >> 6, lane = threadIdx.x & 63;
    int node = blockIdx.x * 4 + wave; // always < NNODES (exact grid)
    int base = row_start[node], end = row_start[node + 1];
    float adv = ad_[node];
    float acc[16];
#pragma unroll
    for (int k = 0; k < 16; ++k) acc[k] = 0.f;
    float ss = 0.f;
    for (int i = base + lane; i < end; i += 64) {   // one iteration for deg<=64
        int sj = csr_src[i];                        // coalesced (consecutive i)
        const float* recf = nrec2 + (size_t)sj * 16;
        const uint4* rec4 = (const uint4*)recf;
        uint4 u0 = rec4[0], u1 = rec4[1];           // g row bf16x16 (32B)
        float as2v = recf[8];                       // as2 (same 64B line)
        float w = edge_w(as2v + adv);
        ss += w;
        unsigned uu[8] = {u0.x, u0.y, u0.z, u0.w, u1.x, u1.y, u1.z, u1.w};
#pragma unroll
        for (int j = 0; j < 8; ++j) {
            acc[2 * j]     += w * __uint_as_float(uu[j] << 16);
            acc[2 * j + 1] += w * __uint_as_float(uu[j] & 0xFFFF0000u);
        }
    }
    // ---- transposed butterfly reduce: lane l ends with total of feature l&15
    // stage bit0: partner l^1 (quad_perm [1,0,3,2] = 0xB1)
#pragma unroll
    for (int j = 0; j < 8; ++j) {
        float keep = (lane & 1) ? acc[2 * j + 1] : acc[2 * j];
        float send = (lane & 1) ? acc[2 * j]     : acc[2 * j + 1];
        acc[j] = keep + dpp_mov<0xB1>(send);
    }
    // stage bit1: partner l^2 (quad_perm [2,3,0,1] = 0x4E)
#pragma unroll
    for (int j = 0; j < 4; ++j) {
        float keep = (lane & 2) ? acc[2 * j + 1] : acc[2 * j];
        float send = (lane & 2) ? acc[2 * j]     : acc[2 * j + 1];
        acc[j] = keep + dpp_mov<0x4E>(send);
    }
    // stage bit2: partner l^4 (ds_swizzle xor4)
#pragma unroll
    for (int j = 0; j < 2; ++j) {
        float keep = (lane & 4) ? acc[2 * j + 1] : acc[2 * j];
        float send = (lane & 4) ? acc[2 * j]     : acc[2 * j + 1];
        acc[j] = keep + swz<0x101F>(send);
    }
    // stage bit3: partner l^8 (ds_swizzle xor8)
    float r;
    {
        float keep = (lane & 8) ? acc[1] : acc[0];
        float send = (lane & 8) ? acc[0] : acc[1];
        r = keep + swz<0x201F>(send);
    }
    // cross-row: xor16 + xor32 -> full-wave total of feature lane&15
    r = swz16_add(r);
    r += __shfl_xor(r, 32);
    float st = wave64_sum(ss);
    // Feature k total lives in lane k (k=0..15): readlane + coalesced W2 column.
    float o = 0.f;
#pragma unroll
    for (int k = 0; k < 16; ++k)
        o += bcast_lane(r, k) * W2[k * 64 + lane];
    o = o / st + b2[lane];                         // single normalize per node
    out[(size_t)node * 64 + lane] = o > 0.f ? o : 0.f;
}

extern "C" void kernel_launch(void* const* d_in, const int* in_sizes, int n_in,
                              void* d_out, int out_size, void* d_ws, size_t ws_size,
                              hipStream_t stream) {
    const float* x     = (const float*)d_in[0];
    const int*   ei    = (const int*)  d_in[1];
    const float* W1    = (const float*)d_in[2];
    const float* as1w  = (const float*)d_in[3];
    const float* ad1w  = (const float*)d_in[4];
    const float* b1    = (const float*)d_in[5];
    const float* W2    = (const float*)d_in[6];
    const float* as2w  = (const float*)d_in[7];
    const float* ad2w  = (const float*)d_in[8];
    const float* b2    = (const float*)d_in[9];
    float* out = (float*)d_out;

    // ws layout (4-byte elems, ~38.8 MB; 40.4 MB proven available):
    //   row_start[N+4] | csr_src[ETOT] | nrec2[N*16 f32 slots = 64B/node] |
    //   adb[N] | ad2b[N] | cvec[64] | pairs[ETOT] | H[M2] | off[M2] |
    //   bsum2[1024] | boff2[1024] | nrec1[N float4]
    int* row_start = (int*)d_ws;
    int* csr_src   = row_start + (NNODES + 4);
    float* nrec2   = (float*)(csr_src + ETOT);   // N*64B: g bf16[16] + as2 + pad
    float* adb     = nrec2 + (size_t)NNODES * 16;
    float* ad2b    = adb + NNODES;
    float* cvec    = ad2b + NNODES;              // 36 floats used
    int* pairs     = (int*)(cvec + 64);          // ETOT
    int* H         = pairs + ETOT;               // M2
    int* off       = H + M2;                     // M2
    int* bsum2     = off + M2;                   // 1024
    int* boff2     = bsum2 + 1024;               // 1024
    float4* nrec1  = (float4*)(boff2 + 1024);    // N*16B: {x0,x1,as1,pad}

    const int B = 256;
    const int NB = (NNODES + B - 1) / B;

    // ---- CSR build: deterministic chunked bucket sort ----
    chunk_hist<<<NCHUNK, 1024, 0, stream>>>(ei, H);
    cscan_local<<<NSB2, 512, 0, stream>>>(H, off, bsum2);
    cscan_bsum<<<1, 1024, 0, stream>>>(bsum2, boff2);
    cscan_add<<<NSB2, 512, 0, stream>>>(off, boff2);
    chunk_scatter<<<NCHUNK, 1024, 0, stream>>>(ei, off, H, pairs);
    fine_sort2<<<NBUCK, B, 0, stream>>>(off, pairs, row_start, csr_src);

    // ---- attention precompute ----
    prep<<<1, 64, 0, stream>>>(W1, as1w, ad1w, W2, as2w, ad2w, cvec);

    // ---- Layer 1: packed node records; aggregate x; W1 in epilogue;
    //      layer-2 record (g bf16 + as2, one 64B line) written fused ----
    alpha1<<<NB, B, 0, stream>>>(x, cvec, nrec1, adb);
    agg_l1<<<NNODES / 4, B, 0, stream>>>(row_start, csr_src, nrec1, adb, W1, b1,
                                         cvec, nrec2, ad2b);

    // ---- Layer 2: aggregate packed records, W2 in epilogue ----
    agg_l2<<<NNODES / 4, B, 0, stream>>>(row_start, csr_src, nrec2, ad2b, W2, b2, out);
}

// Round 10
// 221.097 us; speedup vs baseline: 1.0835x; 1.0464x over previous
//
#include <hip/hip_runtime.h>

#define NNODES 100000
#define NEDGES 3200000
#define ETOT   (NEDGES + NNODES)
#define NEG_SLOPE 0.2f
#define LOG2E 1.4426950408889634f

#define NPB 64                               // nodes per bucket (dst >> 6)
#define NBUCK ((NNODES + NPB - 1) / NPB)     // 1563 buckets
#define NCHUNK 256                           // edge chunks
#define CHUNK_E ((ETOT + NCHUNK - 1) / NCHUNK)  // 12891 edges/chunk
#define M2 (NBUCK * NCHUNK)                  // 400128 (chunk-scan length)
#define NSB2 ((M2 + 511) / 512)              // 782

// bf16 storage via raw ushort — no hip_fp16.h / hip_bf16.h dependency.
__device__ __forceinline__ unsigned short f2bf(float f) {
    unsigned u = __float_as_uint(f);
    u += 0x7FFFu + ((u >> 16) & 1u);         // round-to-nearest-even
    return (unsigned short)(u >> 16);
}
__device__ __forceinline__ float bf2f(unsigned short h) {
    return __uint_as_float(((unsigned)h) << 16);
}

// edge e in [0, NEDGES): src = ei[e], dst = ei[NEDGES+e]
// edge e in [NEDGES, ETOT): self-loop, src = dst = e - NEDGES
__device__ __forceinline__ void edge_sd(int e, const int* __restrict__ ei, int& s, int& d) {
    if (e < NEDGES) { s = ei[e]; d = ei[NEDGES + e]; }
    else            { s = e - NEDGES; d = s; }
}

__device__ __forceinline__ float lrelu(float v) {
    return v > 0.0f ? v : NEG_SLOPE * v;
}

// Alpha tables pre-scaled by log2(e) (round-26): edge weight = single v_exp_f32.
__device__ __forceinline__ float edge_w(float z) {
    return __builtin_amdgcn_exp2f(lrelu(z));
}

// ---- cross-lane primitives ----
template<int CTRL>
__device__ __forceinline__ float dpp_mov(float v) {
    return __int_as_float(__builtin_amdgcn_mov_dpp(__float_as_int(v), CTRL, 0xF, 0xF, true));
}
template<int CTRL>
__device__ __forceinline__ float dpp_add(float v) { return v + dpp_mov<CTRL>(v); }
template<int IMM>
__device__ __forceinline__ float swz(float v) {
    return __int_as_float(__builtin_amdgcn_ds_swizzle(__float_as_int(v), IMM));
}
// xor-16 within each 32-lane group (BitMode masks are 5-bit => group-of-32 local).
__device__ __forceinline__ float swz16_add(float v) { return v + swz<0x401F>(v); }
// Sum over all 16 lanes of each row (rotations 1,2,4,8).
__device__ __forceinline__ float row16_sum(float v) {
    v = dpp_add<0x121>(v);   // row_ror:1
    v = dpp_add<0x122>(v);   // row_ror:2
    v = dpp_add<0x124>(v);   // row_ror:4
    v = dpp_add<0x128>(v);   // row_ror:8
    return v;
}
// Sum over a 32-lane half; every lane of the half ends with the half's total.
__device__ __forceinline__ float half32_sum(float v) {
    v = row16_sum(v);
    v = swz16_add(v);
    return v;
}

// ---------------- deterministic chunked bucket sort ----------------

__global__ void chunk_hist(const int* __restrict__ ei, int* __restrict__ H) {
    __shared__ int h[NBUCK];
    int c = blockIdx.x;
    for (int i = threadIdx.x; i < NBUCK; i += blockDim.x) h[i] = 0;
    __syncthreads();
    int lo = c * CHUNK_E, hi = lo + CHUNK_E; if (hi > ETOT) hi = ETOT;
    for (int e = lo + threadIdx.x; e < hi; e += blockDim.x) {
        int d = (e < NEDGES) ? ei[NEDGES + e] : (e - NEDGES);
        atomicAdd(&h[d >> 6], 1);
    }
    __syncthreads();
    for (int i = threadIdx.x; i < NBUCK; i += blockDim.x) H[c * NBUCK + i] = h[i];
}

// 3-phase exclusive scan of H in bucket-major order.
// Linear index i = b*NCHUNK + c (NCHUNK=256: b = i>>8, c = i&255); value = H[c*NBUCK+b].
__global__ void cscan_local(const int* __restrict__ H, int* __restrict__ off,
                            int* __restrict__ bsum2) {
    __shared__ int arr[512];
    int blk = blockIdx.x, t = threadIdx.x;
    int i = blk * 512 + t;
    int v = (i < M2) ? H[(i & (NCHUNK - 1)) * NBUCK + (i >> 8)] : 0;
    arr[t] = v;
    __syncthreads();
    for (int o = 1; o < 512; o <<= 1) {
        int u = (t >= o) ? arr[t - o] : 0;
        __syncthreads();
        arr[t] += u;
        __syncthreads();
    }
    if (i < M2) off[i] = arr[t] - v;
    if (t == 511) bsum2[blk] = arr[t];
}

__global__ void cscan_bsum(const int* __restrict__ bsum2, int* __restrict__ boff2) {
    __shared__ int arr[1024];
    int t = threadIdx.x;
    int v = (t < NSB2) ? bsum2[t] : 0;
    arr[t] = v;
    __syncthreads();
    for (int o = 1; o < 1024; o <<= 1) {
        int u = (t >= o) ? arr[t - o] : 0;
        __syncthreads();
        arr[t] += u;
        __syncthreads();
    }
    if (t < NSB2) boff2[t] = arr[t] - v;
}

__global__ void cscan_add(int* __restrict__ off, const int* __restrict__ boff2) {
    int i = blockIdx.x * 512 + threadIdx.x;
    if (i < M2) off[i] += boff2[blockIdx.x];
}

// LDS-staged scatter (round-22, proven: WRITE_SIZE 67-78MB -> off top-5).
__global__ __launch_bounds__(1024)
void chunk_scatter(const int* __restrict__ ei, const int* __restrict__ off,
                   const int* __restrict__ H, int* __restrict__ pairs) {
    __shared__ int plds[CHUNK_E];            // 51564 B: packed pair per local slot
    __shared__ unsigned short blds[CHUNK_E]; // 25782 B: bucket id per local slot
    __shared__ int sc[2048];                 //  8192 B: inclusive scan of counts
    __shared__ int lcur[NBUCK];              //  6252 B: local alloc cursor
    __shared__ int gbase[NBUCK];             //  6252 B: off[b,c] - lpref[b]
    int c = blockIdx.x, t = threadIdx.x;
    for (int b = t; b < 2048; b += 1024) sc[b] = (b < NBUCK) ? H[c * NBUCK + b] : 0;
    __syncthreads();
    for (int o = 1; o < 2048; o <<= 1) {
        int i1 = t + 1024;
        int v0 = (t >= o) ? sc[t - o] : 0;
        int v1 = (i1 >= o) ? sc[i1 - o] : 0;
        __syncthreads();
        sc[t] += v0; sc[i1] += v1;
        __syncthreads();
    }
    for (int b = t; b < NBUCK; b += 1024) {
        int excl = (b == 0) ? 0 : sc[b - 1];        // exclusive local prefix
        lcur[b]  = excl;
        gbase[b] = off[b * NCHUNK + c] - excl;
    }
    __syncthreads();
    int lo = c * CHUNK_E, hi = lo + CHUNK_E; if (hi > ETOT) hi = ETOT;
    int n = hi - lo;
    for (int e = lo + t; e < hi; e += 1024) {
        int s, d; edge_sd(e, ei, s, d);
        int b = d >> 6;
        int slot = atomicAdd(&lcur[b], 1);
        plds[slot] = ((d & 63) << 17) | s;          // src < 2^17
        blds[slot] = (unsigned short)b;
    }
    __syncthreads();
    for (int i = t; i < n; i += 1024)
        pairs[gbase[blds[i]] + i] = plds[i];        // coalesced within segments
}

__global__ void fine_sort2(const int* __restrict__ off, const int* __restrict__ pairs,
                           int* __restrict__ row_start, int* __restrict__ csr_src) {
    __shared__ int arr[NPB];
    __shared__ int cur[NPB];
    int b = blockIdx.x;
    int t = threadIdx.x;
    int base = off[b * NCHUNK];
    int bend = (b == NBUCK - 1) ? ETOT : off[(b + 1) * NCHUNK];
    if (t < NPB) arr[t] = 0;
    __syncthreads();
    for (int i = base + t; i < bend; i += blockDim.x)
        atomicAdd(&arr[pairs[i] >> 17], 1);
    __syncthreads();
    int v = (t < NPB) ? arr[t] : 0;
    __syncthreads();
    for (int o = 1; o < NPB; o <<= 1) {           // inclusive scan over 64 counts
        int u = (t < NPB && t >= o) ? arr[t - o] : 0;
        __syncthreads();
        if (t < NPB) arr[t] += u;
        __syncthreads();
    }
    if (t < NPB) {
        int node = b * NPB + t;
        int start = base + arr[t] - v;            // exclusive prefix
        cur[t] = start;
        if (node < NNODES) row_start[node] = start;
    }
    if (b == NBUCK - 1 && t == 0) row_start[NNODES] = ETOT;
    __syncthreads();
    for (int i = base + t; i < bend; i += blockDim.x) {
        int p = pairs[i];
        int slot = atomicAdd(&cur[p >> 17], 1);
        csr_src[slot] = p & 0x1FFFF;
    }
}

// ---------------- attention-vector precompute ----------------
// cvec layout: [0,1]=c1s  [2,3]=c1d  [4..19]=c2s  [20..35]=c2d (log2e-prescaled)
__global__ void prep(const float* __restrict__ W1, const float* __restrict__ as1,
                     const float* __restrict__ ad1, const float* __restrict__ W2,
                     const float* __restrict__ as2, const float* __restrict__ ad2,
                     float* __restrict__ cvec) {
    int t = threadIdx.x;
    if (t < 2) {
        float s = 0.f, d = 0.f;
        for (int f = 0; f < 16; ++f) { s += W1[t * 16 + f] * as1[f]; d += W1[t * 16 + f] * ad1[f]; }
        cvec[t] = s * LOG2E; cvec[2 + t] = d * LOG2E;
    }
    if (t < 16) {
        float s = 0.f, d = 0.f;
        for (int f = 0; f < 64; ++f) { s += W2[t * 64 + f] * as2[f]; d += W2[t * 64 + f] * ad2[f]; }
        cvec[4 + t] = s * LOG2E; cvec[20 + t] = d * LOG2E;
    }
}

// Layer-1 node record (16B, one line per edge gather): {x0, x1, as1, pad}.
__global__ void alpha1(const float* __restrict__ x, const float* __restrict__ cvec,
                       float4* __restrict__ nrec1, float* __restrict__ ad_) {
    int n = blockIdx.x * blockDim.x + threadIdx.x;
    if (n >= NNODES) return;
    float2 xv = ((const float2*)x)[n];
    float as = xv.x * cvec[0] + xv.y * cvec[1];
    ad_[n] = xv.x * cvec[2] + xv.y * cvec[3];
    nrec1[n] = make_float4(xv.x, xv.y, as, 0.f);
}

// ---------------- layer 1: aggregate x (2 feats), @W1 in epilogue -------------
// Round-28: TWO NODES PER WAVE, 32 lanes each. Avg degree 33 meant ~half the
// lanes of a 1-node wave sat EXEC-masked through the edge loop while still
// costing full issue. 32-lane halves cut per-node loop issue ~24%. All
// reduction primitives (row_ror, quad_perm, ds_swizzle 5-bit masks) are
// 32-lane-local, so both halves reduce independently; shfl_xor(32) deleted.
__global__ void agg_l1(const int* __restrict__ row_start, const int* __restrict__ csr_src,
                       const float4* __restrict__ nrec1, const float* __restrict__ ad_,
                       const float* __restrict__ W1, const float* __restrict__ b1,
                       const float* __restrict__ cvec,
                       float* __restrict__ nrec2, float* __restrict__ ad2_) {
    int wave = threadIdx.x >> 6;
    int half = (threadIdx.x >> 5) & 1;
    int hlane = threadIdx.x & 31;
    int node = blockIdx.x * 8 + wave * 2 + half;   // exact grid: NNODES/8 blocks
    int base = row_start[node], end = row_start[node + 1];
    float adv = ad_[node];
    float a0 = 0.f, a1 = 0.f, ss = 0.f;
    for (int i = base + hlane; i < end; i += 32) {
        int sj = csr_src[i];
        float4 r = nrec1[sj];                  // ONE 16B gather: x0,x1,as1
        float w = edge_w(r.z + adv);
        ss += w;
        a0 += w * r.x;
        a1 += w * r.y;
    }
    a0 = half32_sum(a0); a1 = half32_sum(a1); ss = half32_sum(ss);
    int f = hlane & 15;                        // both rows compute feature f
    float v = (a0 * W1[f] + a1 * W1[16 + f]) / ss + b1[f];
    float vr = v > 0.f ? v : 0.f;
    unsigned short* grow = (unsigned short*)(nrec2 + (size_t)node * 16);
    if (hlane < 16) grow[hlane] = f2bf(vr);    // bf16 g row, bytes 0..31
    // fused alpha2 (f32): row-local 16-feature sums (each row holds f=0..15)
    float s2 = vr * cvec[4 + f];
    float d2 = vr * cvec[20 + f];
    s2 = row16_sum(s2); d2 = row16_sum(d2);
    if (hlane == 0) {
        nrec2[(size_t)node * 16 + 8] = s2;     // as2 at bytes 32..35 (same line)
        ad2_[node] = d2;
    }
}

// ---------------- layer 2: aggregate bf16 g, @W2 in epilogue ------------------
// Two nodes per wave, 32 lanes each (round-28); one 64B record line per edge
// (round-27); transposed butterfly reduce (round-25) — stages bits 0..3 +
// xor16 are all 32-lane-local, so each half reduces its own node; the
// shfl_xor(32) stage is gone. Per-half totals bounce through wave-local LDS
// (no barrier: DS ops are in-order within a wave); each lane then produces 2
// of its node's 64 outputs.
__global__ void agg_l2(const int* __restrict__ row_start, const int* __restrict__ csr_src,
                       const float* __restrict__ nrec2, const float* __restrict__ ad_,
                       const float* __restrict__ W2, const float* __restrict__ b2,
                       float* __restrict__ out) {
    __shared__ float tot[4][2][16];
    int wave = threadIdx.x >> 6;
    int half = (threadIdx.x >> 5) & 1;
    int hlane = threadIdx.x & 31;
    int node = blockIdx.x * 8 + wave * 2 + half;   // exact grid: NNODES/8 blocks
    int base = row_start[node], end = row_start[node + 1];
    float adv = ad_[node];
    float acc[16];
#pragma unroll
    for (int k = 0; k < 16; ++k) acc[k] = 0.f;
    float ss = 0.f;
    for (int i = base + hlane; i < end; i += 32) {
        int sj = csr_src[i];                        // coalesced (consecutive i)
        const float* recf = nrec2 + (size_t)sj * 16;
        const uint4* rec4 = (const uint4*)recf;
        uint4 u0 = rec4[0], u1 = rec4[1];           // g row bf16x16 (32B)
        float as2v = recf[8];                       // as2 (same 64B line)
        float w = edge_w(as2v + adv);
        ss += w;
        unsigned uu[8] = {u0.x, u0.y, u0.z, u0.w, u1.x, u1.y, u1.z, u1.w};
#pragma unroll
        for (int j = 0; j < 8; ++j) {
            acc[2 * j]     += w * __uint_as_float(uu[j] << 16);
            acc[2 * j + 1] += w * __uint_as_float(uu[j] & 0xFFFF0000u);
        }
    }
    // ---- transposed butterfly (within 16-lane rows): lane l -> feature l&15
    // stage bit0: partner l^1 (quad_perm [1,0,3,2] = 0xB1)
#pragma unroll
    for (int j = 0; j < 8; ++j) {
        float keep = (hlane & 1) ? acc[2 * j + 1] : acc[2 * j];
        float send = (hlane & 1) ? acc[2 * j]     : acc[2 * j + 1];
        acc[j] = keep + dpp_mov<0xB1>(send);
    }
    // stage bit1: partner l^2 (quad_perm [2,3,0,1] = 0x4E)
#pragma unroll
    for (int j = 0; j < 4; ++j) {
        float keep = (hlane & 2) ? acc[2 * j + 1] : acc[2 * j];
        float send = (hlane & 2) ? acc[2 * j]     : acc[2 * j + 1];
        acc[j] = keep + dpp_mov<0x4E>(send);
    }
    // stage bit2: partner l^4 (ds_swizzle xor4)
#pragma unroll
    for (int j = 0; j < 2; ++j) {
        float keep = (hlane & 4) ? acc[2 * j + 1] : acc[2 * j];
        float send = (hlane & 4) ? acc[2 * j]     : acc[2 * j + 1];
        acc[j] = keep + swz<0x101F>(send);
    }
    // stage bit3: partner l^8 (ds_swizzle xor8)
    float r;
    {
        float keep = (hlane & 8) ? acc[1] : acc[0];
        float send = (hlane & 8) ? acc[0] : acc[1];
        r = keep + swz<0x201F>(send);
    }
    // combine this half's two rows: xor16 (32-lane-local) -> per-node totals
    r = swz16_add(r);
    float st = half32_sum(ss);
    // Totals of this half's node live in its lanes 0..15 (dup 16..31): bounce
    // through wave-local LDS so every lane sees all 16 (in-order DS, no barrier).
    if (hlane < 16) tot[wave][half][hlane] = r;
    float o0 = 0.f, o1 = 0.f;
#pragma unroll
    for (int k = 0; k < 16; ++k) {
        float t = tot[wave][half][k];
        o0 += t * W2[k * 64 + hlane];               // coalesced W2 columns
        o1 += t * W2[k * 64 + 32 + hlane];
    }
    float inv = 1.0f / st;
    o0 = o0 * inv + b2[hlane];
    o1 = o1 * inv + b2[32 + hlane];
    out[(size_t)node * 64 + hlane]      = o0 > 0.f ? o0 : 0.f;
    out[(size_t)node * 64 + 32 + hlane] = o1 > 0.f ? o1 : 0.f;
}

extern "C" void kernel_launch(void* const* d_in, const int* in_sizes, int n_in,
                              void* d_out, int out_size, void* d_ws, size_t ws_size,
                              hipStream_t stream) {
    const float* x     = (const float*)d_in[0];
    const int*   ei    = (const int*)  d_in[1];
    const float* W1    = (const float*)d_in[2];
    const float* as1w  = (const float*)d_in[3];
    const float* ad1w  = (const float*)d_in[4];
    const float* b1    = (const float*)d_in[5];
    const float* W2    = (const float*)d_in[6];
    const float* as2w  = (const float*)d_in[7];
    const float* ad2w  = (const float*)d_in[8];
    const float* b2    = (const float*)d_in[9];
    float* out = (float*)d_out;

    // ws layout (4-byte elems, ~38.8 MB; 40.4 MB proven available):
    //   row_start[N+4] | csr_src[ETOT] | nrec2[N*16 f32 slots = 64B/node] |
    //   adb[N] | ad2b[N] | cvec[64] | pairs[ETOT] | H[M2] | off[M2] |
    //   bsum2[1024] | boff2[1024] | nrec1[N float4]
    int* row_start = (int*)d_ws;
    int* csr_src   = row_start + (NNODES + 4);
    float* nrec2   = (float*)(csr_src + ETOT);   // N*64B: g bf16[16] + as2 + pad
    float* adb     = nrec2 + (size_t)NNODES * 16;
    float* ad2b    = adb + NNODES;
    float* cvec    = ad2b + NNODES;              // 36 floats used
    int* pairs     = (int*)(cvec + 64);          // ETOT
    int* H         = pairs + ETOT;               // M2
    int* off       = H + M2;                     // M2
    int* bsum2     = off + M2;                   // 1024
    int* boff2     = bsum2 + 1024;               // 1024
    float4* nrec1  = (float4*)(boff2 + 1024);    // N*16B: {x0,x1,as1,pad}

    const int B = 256;
    const int NB = (NNODES + B - 1) / B;

    // ---- CSR build: deterministic chunked bucket sort ----
    chunk_hist<<<NCHUNK, 1024, 0, stream>>>(ei, H);
    cscan_local<<<NSB2, 512, 0, stream>>>(H, off, bsum2);
    cscan_bsum<<<1, 1024, 0, stream>>>(bsum2, boff2);
    cscan_add<<<NSB2, 512, 0, stream>>>(off, boff2);
    chunk_scatter<<<NCHUNK, 1024, 0, stream>>>(ei, off, H, pairs);
    fine_sort2<<<NBUCK, B, 0, stream>>>(off, pairs, row_start, csr_src);

    // ---- attention precompute ----
    prep<<<1, 64, 0, stream>>>(W1, as1w, ad1w, W2, as2w, ad2w, cvec);

    // ---- Layer 1: packed node records; aggregate x; W1 in epilogue;
    //      layer-2 record (g bf16 + as2, one 64B line) written fused ----
    alpha1<<<NB, B, 0, stream>>>(x, cvec, nrec1, adb);
    agg_l1<<<NNODES / 8, B, 0, stream>>>(row_start, csr_src, nrec1, adb, W1, b1,
                                         cvec, nrec2, ad2b);

    // ---- Layer 2: aggregate packed records, W2 in epilogue ----
    agg_l2<<<NNODES / 8, B, 0, stream>>>(row_start, csr_src, nrec2, ad2b, W2, b2, out);
}

// Round 11
// 215.919 us; speedup vs baseline: 1.1095x; 1.0240x over previous
//
#include <hip/hip_runtime.h>

#define NNODES 100000
#define NEDGES 3200000
#define ETOT   (NEDGES + NNODES)
#define NEG_SLOPE 0.2f
#define LOG2E 1.4426950408889634f

#define NPB 64                               // nodes per bucket (dst >> 6)
#define NBUCK ((NNODES + NPB - 1) / NPB)     // 1563 buckets
#define NCHUNK 256                           // edge chunks
#define CHUNK_E ((ETOT + NCHUNK - 1) / NCHUNK)  // 12891 edges/chunk
#define M2 (NBUCK * NCHUNK)                  // 400128 (chunk-scan length)
#define NSB2 ((M2 + 511) / 512)              // 782
#define FS_CAP 4096                          // fine_sort2 LDS staging capacity

// bf16 storage via raw ushort — no hip_fp16.h / hip_bf16.h dependency.
__device__ __forceinline__ unsigned short f2bf(float f) {
    unsigned u = __float_as_uint(f);
    u += 0x7FFFu + ((u >> 16) & 1u);         // round-to-nearest-even
    return (unsigned short)(u >> 16);
}
__device__ __forceinline__ float bf2f(unsigned short h) {
    return __uint_as_float(((unsigned)h) << 16);
}

// edge e in [0, NEDGES): src = ei[e], dst = ei[NEDGES+e]
// edge e in [NEDGES, ETOT): self-loop, src = dst = e - NEDGES
__device__ __forceinline__ void edge_sd(int e, const int* __restrict__ ei, int& s, int& d) {
    if (e < NEDGES) { s = ei[e]; d = ei[NEDGES + e]; }
    else            { s = e - NEDGES; d = s; }
}

__device__ __forceinline__ float lrelu(float v) {
    return v > 0.0f ? v : NEG_SLOPE * v;
}

// Alpha tables pre-scaled by log2(e) (round-26): edge weight = single v_exp_f32.
__device__ __forceinline__ float edge_w(float z) {
    return __builtin_amdgcn_exp2f(lrelu(z));
}

// ---- cross-lane primitives ----
template<int CTRL>
__device__ __forceinline__ float dpp_mov(float v) {
    return __int_as_float(__builtin_amdgcn_mov_dpp(__float_as_int(v), CTRL, 0xF, 0xF, true));
}
template<int CTRL>
__device__ __forceinline__ float dpp_add(float v) { return v + dpp_mov<CTRL>(v); }
template<int IMM>
__device__ __forceinline__ float swz(float v) {
    return __int_as_float(__builtin_amdgcn_ds_swizzle(__float_as_int(v), IMM));
}
// xor-16 within each 32-lane group (BitMode masks are 5-bit => group-of-32 local).
__device__ __forceinline__ float swz16_add(float v) { return v + swz<0x401F>(v); }
// Sum over all 16 lanes of each row (rotations 1,2,4,8).
__device__ __forceinline__ float row16_sum(float v) {
    v = dpp_add<0x121>(v);   // row_ror:1
    v = dpp_add<0x122>(v);   // row_ror:2
    v = dpp_add<0x124>(v);   // row_ror:4
    v = dpp_add<0x128>(v);   // row_ror:8
    return v;
}
// Sum over a 32-lane half; every lane of the half ends with the half's total.
__device__ __forceinline__ float half32_sum(float v) {
    v = row16_sum(v);
    v = swz16_add(v);
    return v;
}

// ---------------- deterministic chunked bucket sort ----------------

__global__ void chunk_hist(const int* __restrict__ ei, int* __restrict__ H) {
    __shared__ int h[NBUCK];
    int c = blockIdx.x;
    for (int i = threadIdx.x; i < NBUCK; i += blockDim.x) h[i] = 0;
    __syncthreads();
    int lo = c * CHUNK_E, hi = lo + CHUNK_E; if (hi > ETOT) hi = ETOT;
    for (int e = lo + threadIdx.x; e < hi; e += blockDim.x) {
        int d = (e < NEDGES) ? ei[NEDGES + e] : (e - NEDGES);
        atomicAdd(&h[d >> 6], 1);
    }
    __syncthreads();
    for (int i = threadIdx.x; i < NBUCK; i += blockDim.x) H[c * NBUCK + i] = h[i];
}

// 3-phase exclusive scan of H in bucket-major order.
// Linear index i = b*NCHUNK + c (NCHUNK=256: b = i>>8, c = i&255); value = H[c*NBUCK+b].
// Round-29: cscan_add DELETED — consumers fold boff2[b>>1] on the fly
// (i>>9 = b>>1 independent of c, since NCHUNK=256 and scan blocks are 512).
__global__ void cscan_local(const int* __restrict__ H, int* __restrict__ off,
                            int* __restrict__ bsum2) {
    __shared__ int arr[512];
    int blk = blockIdx.x, t = threadIdx.x;
    int i = blk * 512 + t;
    int v = (i < M2) ? H[(i & (NCHUNK - 1)) * NBUCK + (i >> 8)] : 0;
    arr[t] = v;
    __syncthreads();
    for (int o = 1; o < 512; o <<= 1) {
        int u = (t >= o) ? arr[t - o] : 0;
        __syncthreads();
        arr[t] += u;
        __syncthreads();
    }
    if (i < M2) off[i] = arr[t] - v;
    if (t == 511) bsum2[blk] = arr[t];
}

__global__ void cscan_bsum(const int* __restrict__ bsum2, int* __restrict__ boff2) {
    __shared__ int arr[1024];
    int t = threadIdx.x;
    int v = (t < NSB2) ? bsum2[t] : 0;
    arr[t] = v;
    __syncthreads();
    for (int o = 1; o < 1024; o <<= 1) {
        int u = (t >= o) ? arr[t - o] : 0;
        __syncthreads();
        arr[t] += u;
        __syncthreads();
    }
    if (t < NSB2) boff2[t] = arr[t] - v;
}

// LDS-staged scatter (round-22, proven). Round-29: global offset = local off +
// boff2[b>>1] folded on the fly (cscan_add deleted).
__global__ __launch_bounds__(1024)
void chunk_scatter(const int* __restrict__ ei, const int* __restrict__ off,
                   const int* __restrict__ boff2, const int* __restrict__ H,
                   int* __restrict__ pairs) {
    __shared__ int plds[CHUNK_E];            // 51564 B: packed pair per local slot
    __shared__ unsigned short blds[CHUNK_E]; // 25782 B: bucket id per local slot
    __shared__ int sc[2048];                 //  8192 B: inclusive scan of counts
    __shared__ int lcur[NBUCK];              //  6252 B: local alloc cursor
    __shared__ int gbase[NBUCK];             //  6252 B: off_g[b,c] - lpref[b]
    int c = blockIdx.x, t = threadIdx.x;
    for (int b = t; b < 2048; b += 1024) sc[b] = (b < NBUCK) ? H[c * NBUCK + b] : 0;
    __syncthreads();
    for (int o = 1; o < 2048; o <<= 1) {
        int i1 = t + 1024;
        int v0 = (t >= o) ? sc[t - o] : 0;
        int v1 = (i1 >= o) ? sc[i1 - o] : 0;
        __syncthreads();
        sc[t] += v0; sc[i1] += v1;
        __syncthreads();
    }
    for (int b = t; b < NBUCK; b += 1024) {
        int excl = (b == 0) ? 0 : sc[b - 1];        // exclusive local prefix
        lcur[b]  = excl;
        gbase[b] = off[b * NCHUNK + c] + boff2[b >> 1] - excl;
    }
    __syncthreads();
    int lo = c * CHUNK_E, hi = lo + CHUNK_E; if (hi > ETOT) hi = ETOT;
    int n = hi - lo;
    for (int e = lo + t; e < hi; e += 1024) {
        int s, d; edge_sd(e, ei, s, d);
        int b = d >> 6;
        int slot = atomicAdd(&lcur[b], 1);
        plds[slot] = ((d & 63) << 17) | s;          // src < 2^17
        blds[slot] = (unsigned short)b;
    }
    __syncthreads();
    for (int i = t; i < n; i += 1024)
        pairs[gbase[blds[i]] + i] = plds[i];        // coalesced within segments
}

// Round-29: pairs staged in LDS ONCE (was read twice from global: hist pass +
// scatter pass = 26.4MB). Bucket ~2176 edges (64 x Poisson(33) + self-loops);
// FS_CAP=4096 with global-path fallback for adversarial inputs. 512 threads.
__global__ __launch_bounds__(512)
void fine_sort2(const int* __restrict__ off, const int* __restrict__ boff2,
                const int* __restrict__ pairs,
                int* __restrict__ row_start, int* __restrict__ csr_src) {
    __shared__ int sp[FS_CAP];               // 16KB staged pairs
    __shared__ int arr[NPB];
    __shared__ int cur[NPB];
    int b = blockIdx.x;
    int t = threadIdx.x;
    int base = off[b * NCHUNK] + boff2[b >> 1];
    int bend = (b == NBUCK - 1) ? ETOT : off[(b + 1) * NCHUNK] + boff2[(b + 1) >> 1];
    int n = bend - base;
    if (t < NPB) arr[t] = 0;
    __syncthreads();
    bool fits = (n <= FS_CAP);
    if (fits) {
        for (int i = t; i < n; i += 512) {
            int p = pairs[base + i];
            sp[i] = p;
            atomicAdd(&arr[p >> 17], 1);
        }
    } else {
        for (int i = t; i < n; i += 512)
            atomicAdd(&arr[pairs[base + i] >> 17], 1);
    }
    __syncthreads();
    int v = (t < NPB) ? arr[t] : 0;
    __syncthreads();
    for (int o = 1; o < NPB; o <<= 1) {           // inclusive scan over 64 counts
        int u = (t < NPB && t >= o) ? arr[t - o] : 0;
        __syncthreads();
        if (t < NPB) arr[t] += u;
        __syncthreads();
    }
    if (t < NPB) {
        int node = b * NPB + t;
        int start = base + arr[t] - v;            // exclusive prefix
        cur[t] = start;
        if (node < NNODES) row_start[node] = start;
    }
    if (b == NBUCK - 1 && t == 0) row_start[NNODES] = ETOT;
    __syncthreads();
    if (fits) {
        for (int i = t; i < n; i += 512) {
            int p = sp[i];
            int slot = atomicAdd(&cur[p >> 17], 1);
            csr_src[slot] = p & 0x1FFFF;
        }
    } else {
        for (int i = t; i < n; i += 512) {
            int p = pairs[base + i];
            int slot = atomicAdd(&cur[p >> 17], 1);
            csr_src[slot] = p & 0x1FFFF;
        }
    }
}

// ---------------- attention-vector precompute ----------------
// cvec layout: [0,1]=c1s  [2,3]=c1d  [4..19]=c2s  [20..35]=c2d (log2e-prescaled)
__global__ void prep(const float* __restrict__ W1, const float* __restrict__ as1,
                     const float* __restrict__ ad1, const float* __restrict__ W2,
                     const float* __restrict__ as2, const float* __restrict__ ad2,
                     float* __restrict__ cvec) {
    int t = threadIdx.x;
    if (t < 2) {
        float s = 0.f, d = 0.f;
        for (int f = 0; f < 16; ++f) { s += W1[t * 16 + f] * as1[f]; d += W1[t * 16 + f] * ad1[f]; }
        cvec[t] = s * LOG2E; cvec[2 + t] = d * LOG2E;
    }
    if (t < 16) {
        float s = 0.f, d = 0.f;
        for (int f = 0; f < 64; ++f) { s += W2[t * 64 + f] * as2[f]; d += W2[t * 64 + f] * ad2[f]; }
        cvec[4 + t] = s * LOG2E; cvec[20 + t] = d * LOG2E;
    }
}

// Layer-1 node record (16B, one line per edge gather): {x0, x1, as1, pad}.
__global__ void alpha1(const float* __restrict__ x, const float* __restrict__ cvec,
                       float4* __restrict__ nrec1, float* __restrict__ ad_) {
    int n = blockIdx.x * blockDim.x + threadIdx.x;
    if (n >= NNODES) return;
    float2 xv = ((const float2*)x)[n];
    float as = xv.x * cvec[0] + xv.y * cvec[1];
    ad_[n] = xv.x * cvec[2] + xv.y * cvec[3];
    nrec1[n] = make_float4(xv.x, xv.y, as, 0.f);
}

// ---------------- layer 1: aggregate x (2 feats), @W1 in epilogue -------------
// Two nodes per wave, 32 lanes each (round-28); one 16B record gather per edge
// (round-27); 32-lane-local DPP/swz reduction; alpha2 fused in epilogue.
__global__ void agg_l1(const int* __restrict__ row_start, const int* __restrict__ csr_src,
                       const float4* __restrict__ nrec1, const float* __restrict__ ad_,
                       const float* __restrict__ W1, const float* __restrict__ b1,
                       const float* __restrict__ cvec,
                       float* __restrict__ nrec2, float* __restrict__ ad2_) {
    int wave = threadIdx.x >> 6;
    int half = (threadIdx.x >> 5) & 1;
    int hlane = threadIdx.x & 31;
    int node = blockIdx.x * 8 + wave * 2 + half;   // exact grid: NNODES/8 blocks
    int base = row_start[node], end = row_start[node + 1];
    float adv = ad_[node];
    float a0 = 0.f, a1 = 0.f, ss = 0.f;
    for (int i = base + hlane; i < end; i += 32) {
        int sj = csr_src[i];
        float4 r = nrec1[sj];                  // ONE 16B gather: x0,x1,as1
        float w = edge_w(r.z + adv);
        ss += w;
        a0 += w * r.x;
        a1 += w * r.y;
    }
    a0 = half32_sum(a0); a1 = half32_sum(a1); ss = half32_sum(ss);
    int f = hlane & 15;                        // both rows compute feature f
    float v = (a0 * W1[f] + a1 * W1[16 + f]) / ss + b1[f];
    float vr = v > 0.f ? v : 0.f;
    unsigned short* grow = (unsigned short*)(nrec2 + (size_t)node * 16);
    if (hlane < 16) grow[hlane] = f2bf(vr);    // bf16 g row, bytes 0..31
    // fused alpha2 (f32): row-local 16-feature sums (each row holds f=0..15)
    float s2 = vr * cvec[4 + f];
    float d2 = vr * cvec[20 + f];
    s2 = row16_sum(s2); d2 = row16_sum(d2);
    if (hlane == 0) {
        nrec2[(size_t)node * 16 + 8] = s2;     // as2 at bytes 32..35 (same line)
        ad2_[node] = d2;
    }
}

// ---------------- layer 2: aggregate bf16 g, @W2 in epilogue ------------------
// Two nodes per wave, 32 lanes each (round-28); one 64B record line per edge
// (round-27); transposed butterfly reduce (round-25), all 32-lane-local;
// per-half totals bounce through wave-local LDS (in-order DS, no barrier).
__global__ void agg_l2(const int* __restrict__ row_start, const int* __restrict__ csr_src,
                       const float* __restrict__ nrec2, const float* __restrict__ ad_,
                       const float* __restrict__ W2, const float* __restrict__ b2,
                       float* __restrict__ out) {
    __shared__ float tot[4][2][16];
    int wave = threadIdx.x >> 6;
    int half = (threadIdx.x >> 5) & 1;
    int hlane = threadIdx.x & 31;
    int node = blockIdx.x * 8 + wave * 2 + half;   // exact grid: NNODES/8 blocks
    int base = row_start[node], end = row_start[node + 1];
    float adv = ad_[node];
    float acc[16];
#pragma unroll
    for (int k = 0; k < 16; ++k) acc[k] = 0.f;
    float ss = 0.f;
    for (int i = base + hlane; i < end; i += 32) {
        int sj = csr_src[i];                        // coalesced (consecutive i)
        const float* recf = nrec2 + (size_t)sj * 16;
        const uint4* rec4 = (const uint4*)recf;
        uint4 u0 = rec4[0], u1 = rec4[1];           // g row bf16x16 (32B)
        float as2v = recf[8];                       // as2 (same 64B line)
        float w = edge_w(as2v + adv);
        ss += w;
        unsigned uu[8] = {u0.x, u0.y, u0.z, u0.w, u1.x, u1.y, u1.z, u1.w};
#pragma unroll
        for (int j = 0; j < 8; ++j) {
            acc[2 * j]     += w * __uint_as_float(uu[j] << 16);
            acc[2 * j + 1] += w * __uint_as_float(uu[j] & 0xFFFF0000u);
        }
    }
    // ---- transposed butterfly (within 16-lane rows): lane l -> feature l&15
    // stage bit0: partner l^1 (quad_perm [1,0,3,2] = 0xB1)
#pragma unroll
    for (int j = 0; j < 8; ++j) {
        float keep = (hlane & 1) ? acc[2 * j + 1] : acc[2 * j];
        float send = (hlane & 1) ? acc[2 * j]     : acc[2 * j + 1];
        acc[j] = keep + dpp_mov<0xB1>(send);
    }
    // stage bit1: partner l^2 (quad_perm [2,3,0,1] = 0x4E)
#pragma unroll
    for (int j = 0; j < 4; ++j) {
        float keep = (hlane & 2) ? acc[2 * j + 1] : acc[2 * j];
        float send = (hlane & 2) ? acc[2 * j]     : acc[2 * j + 1];
        acc[j] = keep + dpp_mov<0x4E>(send);
    }
    // stage bit2: partner l^4 (ds_swizzle xor4)
#pragma unroll
    for (int j = 0; j < 2; ++j) {
        float keep = (hlane & 4) ? acc[2 * j + 1] : acc[2 * j];
        float send = (hlane & 4) ? acc[2 * j]     : acc[2 * j + 1];
        acc[j] = keep + swz<0x101F>(send);
    }
    // stage bit3: partner l^8 (ds_swizzle xor8)
    float r;
    {
        float keep = (hlane & 8) ? acc[1] : acc[0];
        float send = (hlane & 8) ? acc[0] : acc[1];
        r = keep + swz<0x201F>(send);
    }
    // combine this half's two rows: xor16 (32-lane-local) -> per-node totals
    r = swz16_add(r);
    float st = half32_sum(ss);
    // Totals of this half's node live in its lanes 0..15 (dup 16..31): bounce
    // through wave-local LDS so every lane sees all 16 (in-order DS, no barrier).
    if (hlane < 16) tot[wave][half][hlane] = r;
    float o0 = 0.f, o1 = 0.f;
#pragma unroll
    for (int k = 0; k < 16; ++k) {
        float t = tot[wave][half][k];
        o0 += t * W2[k * 64 + hlane];               // coalesced W2 columns
        o1 += t * W2[k * 64 + 32 + hlane];
    }
    float inv = 1.0f / st;
    o0 = o0 * inv + b2[hlane];
    o1 = o1 * inv + b2[32 + hlane];
    out[(size_t)node * 64 + hlane]      = o0 > 0.f ? o0 : 0.f;
    out[(size_t)node * 64 + 32 + hlane] = o1 > 0.f ? o1 : 0.f;
}

extern "C" void kernel_launch(void* const* d_in, const int* in_sizes, int n_in,
                              void* d_out, int out_size, void* d_ws, size_t ws_size,
                              hipStream_t stream) {
    const float* x     = (const float*)d_in[0];
    const int*   ei    = (const int*)  d_in[1];
    const float* W1    = (const float*)d_in[2];
    const float* as1w  = (const float*)d_in[3];
    const float* ad1w  = (const float*)d_in[4];
    const float* b1    = (const float*)d_in[5];
    const float* W2    = (const float*)d_in[6];
    const float* as2w  = (const float*)d_in[7];
    const float* ad2w  = (const float*)d_in[8];
    const float* b2    = (const float*)d_in[9];
    float* out = (float*)d_out;

    // ws layout (4-byte elems, ~38.8 MB; 40.4 MB proven available):
    //   row_start[N+4] | csr_src[ETOT] | nrec2[N*16 f32 slots = 64B/node] |
    //   adb[N] | ad2b[N] | cvec[64] | pairs[ETOT] | H[M2] | off[M2] |
    //   bsum2[1024] | boff2[1024] | nrec1[N float4]
    int* row_start = (int*)d_ws;
    int* csr_src   = row_start + (NNODES + 4);
    float* nrec2   = (float*)(csr_src + ETOT);   // N*64B: g bf16[16] + as2 + pad
    float* adb     = nrec2 + (size_t)NNODES * 16;
    float* ad2b    = adb + NNODES;
    float* cvec    = ad2b + NNODES;              // 36 floats used
    int* pairs     = (int*)(cvec + 64);          // ETOT
    int* H         = pairs + ETOT;               // M2
    int* off       = H + M2;                     // M2
    int* bsum2     = off + M2;                   // 1024
    int* boff2     = bsum2 + 1024;               // 1024
    float4* nrec1  = (float4*)(boff2 + 1024);    // N*16B: {x0,x1,as1,pad}

    const int B = 256;
    const int NB = (NNODES + B - 1) / B;

    // ---- CSR build: deterministic chunked bucket sort (cscan_add folded away) ----
    chunk_hist<<<NCHUNK, 1024, 0, stream>>>(ei, H);
    cscan_local<<<NSB2, 512, 0, stream>>>(H, off, bsum2);
    cscan_bsum<<<1, 1024, 0, stream>>>(bsum2, boff2);
    chunk_scatter<<<NCHUNK, 1024, 0, stream>>>(ei, off, boff2, H, pairs);
    fine_sort2<<<NBUCK, 512, 0, stream>>>(off, boff2, pairs, row_start, csr_src);

    // ---- attention precompute ----
    prep<<<1, 64, 0, stream>>>(W1, as1w, ad1w, W2, as2w, ad2w, cvec);

    // ---- Layer 1: packed node records; aggregate x; W1 in epilogue;
    //      layer-2 record (g bf16 + as2, one 64B line) written fused ----
    alpha1<<<NB, B, 0, stream>>>(x, cvec, nrec1, adb);
    agg_l1<<<NNODES / 8, B, 0, stream>>>(row_start, csr_src, nrec1, adb, W1, b1,
                                         cvec, nrec2, ad2b);

    // ---- Layer 2: aggregate packed records, W2 in epilogue ----
    agg_l2<<<NNODES / 8, B, 0, stream>>>(row_start, csr_src, nrec2, ad2b, W2, b2, out);
}

// Round 12
// 211.151 us; speedup vs baseline: 1.1346x; 1.0226x over previous
//
#include <hip/hip_runtime.h>

#define NNODES 100000
#define NEDGES 3200000
#define ETOT   (NEDGES + NNODES)
#define NEG_SLOPE 0.2f
#define LOG2E 1.4426950408889634f

#define NPB 64                               // nodes per bucket (dst >> 6)
#define NBUCK ((NNODES + NPB - 1) / NPB)     // 1563 buckets
#define NCHUNK 256                           // edge chunks
#define CHUNK_E ((ETOT + NCHUNK - 1) / NCHUNK)  // 12891 edges/chunk
#define M2 (NBUCK * NCHUNK)                  // 400128 (chunk-scan length)
#define NSB2 ((M2 + 511) / 512)              // 782
#define FS_CAP 4096                          // fine_agg1 LDS staging capacity

// bf16 storage via raw ushort — no hip_fp16.h / hip_bf16.h dependency.
__device__ __forceinline__ unsigned short f2bf(float f) {
    unsigned u = __float_as_uint(f);
    u += 0x7FFFu + ((u >> 16) & 1u);         // round-to-nearest-even
    return (unsigned short)(u >> 16);
}
__device__ __forceinline__ float bf2f(unsigned short h) {
    return __uint_as_float(((unsigned)h) << 16);
}

// edge e in [0, NEDGES): src = ei[e], dst = ei[NEDGES+e]
// edge e in [NEDGES, ETOT): self-loop, src = dst = e - NEDGES
__device__ __forceinline__ void edge_sd(int e, const int* __restrict__ ei, int& s, int& d) {
    if (e < NEDGES) { s = ei[e]; d = ei[NEDGES + e]; }
    else            { s = e - NEDGES; d = s; }
}

__device__ __forceinline__ float lrelu(float v) {
    return v > 0.0f ? v : NEG_SLOPE * v;
}

// Alpha tables pre-scaled by log2(e) (round-26): edge weight = single v_exp_f32.
__device__ __forceinline__ float edge_w(float z) {
    return __builtin_amdgcn_exp2f(lrelu(z));
}

// ---- cross-lane primitives ----
template<int CTRL>
__device__ __forceinline__ float dpp_mov(float v) {
    return __int_as_float(__builtin_amdgcn_mov_dpp(__float_as_int(v), CTRL, 0xF, 0xF, true));
}
template<int CTRL>
__device__ __forceinline__ float dpp_add(float v) { return v + dpp_mov<CTRL>(v); }
template<int IMM>
__device__ __forceinline__ float swz(float v) {
    return __int_as_float(__builtin_amdgcn_ds_swizzle(__float_as_int(v), IMM));
}
// xor-16 within each 32-lane group (BitMode masks are 5-bit => group-of-32 local).
__device__ __forceinline__ float swz16_add(float v) { return v + swz<0x401F>(v); }
// Sum over all 16 lanes of each row (rotations 1,2,4,8).
__device__ __forceinline__ float row16_sum(float v) {
    v = dpp_add<0x121>(v);   // row_ror:1
    v = dpp_add<0x122>(v);   // row_ror:2
    v = dpp_add<0x124>(v);   // row_ror:4
    v = dpp_add<0x128>(v);   // row_ror:8
    return v;
}
// Sum over a 32-lane half; every lane of the half ends with the half's total.
__device__ __forceinline__ float half32_sum(float v) {
    v = row16_sum(v);
    v = swz16_add(v);
    return v;
}

// ---------------- deterministic chunked bucket sort ----------------

__global__ void chunk_hist(const int* __restrict__ ei, int* __restrict__ H) {
    __shared__ int h[NBUCK];
    int c = blockIdx.x;
    for (int i = threadIdx.x; i < NBUCK; i += blockDim.x) h[i] = 0;
    __syncthreads();
    int lo = c * CHUNK_E, hi = lo + CHUNK_E; if (hi > ETOT) hi = ETOT;
    for (int e = lo + threadIdx.x; e < hi; e += blockDim.x) {
        int d = (e < NEDGES) ? ei[NEDGES + e] : (e - NEDGES);
        atomicAdd(&h[d >> 6], 1);
    }
    __syncthreads();
    for (int i = threadIdx.x; i < NBUCK; i += blockDim.x) H[c * NBUCK + i] = h[i];
}

// 3-phase exclusive scan of H in bucket-major order (cscan_add folded away:
// consumers apply boff2[b>>1] on the fly since i>>9 = b>>1 is c-independent).
__global__ void cscan_local(const int* __restrict__ H, int* __restrict__ off,
                            int* __restrict__ bsum2) {
    __shared__ int arr[512];
    int blk = blockIdx.x, t = threadIdx.x;
    int i = blk * 512 + t;
    int v = (i < M2) ? H[(i & (NCHUNK - 1)) * NBUCK + (i >> 8)] : 0;
    arr[t] = v;
    __syncthreads();
    for (int o = 1; o < 512; o <<= 1) {
        int u = (t >= o) ? arr[t - o] : 0;
        __syncthreads();
        arr[t] += u;
        __syncthreads();
    }
    if (i < M2) off[i] = arr[t] - v;
    if (t == 511) bsum2[blk] = arr[t];
}

__global__ void cscan_bsum(const int* __restrict__ bsum2, int* __restrict__ boff2) {
    __shared__ int arr[1024];
    int t = threadIdx.x;
    int v = (t < NSB2) ? bsum2[t] : 0;
    arr[t] = v;
    __syncthreads();
    for (int o = 1; o < 1024; o <<= 1) {
        int u = (t >= o) ? arr[t - o] : 0;
        __syncthreads();
        arr[t] += u;
        __syncthreads();
    }
    if (t < NSB2) boff2[t] = arr[t] - v;
}

// LDS-staged scatter (round-22, proven). Global offset = local off + boff2[b>>1].
__global__ __launch_bounds__(1024)
void chunk_scatter(const int* __restrict__ ei, const int* __restrict__ off,
                   const int* __restrict__ boff2, const int* __restrict__ H,
                   int* __restrict__ pairs) {
    __shared__ int plds[CHUNK_E];            // 51564 B: packed pair per local slot
    __shared__ unsigned short blds[CHUNK_E]; // 25782 B: bucket id per local slot
    __shared__ int sc[2048];                 //  8192 B: inclusive scan of counts
    __shared__ int lcur[NBUCK];              //  6252 B: local alloc cursor
    __shared__ int gbase[NBUCK];             //  6252 B: off_g[b,c] - lpref[b]
    int c = blockIdx.x, t = threadIdx.x;
    for (int b = t; b < 2048; b += 1024) sc[b] = (b < NBUCK) ? H[c * NBUCK + b] : 0;
    __syncthreads();
    for (int o = 1; o < 2048; o <<= 1) {
        int i1 = t + 1024;
        int v0 = (t >= o) ? sc[t - o] : 0;
        int v1 = (i1 >= o) ? sc[i1 - o] : 0;
        __syncthreads();
        sc[t] += v0; sc[i1] += v1;
        __syncthreads();
    }
    for (int b = t; b < NBUCK; b += 1024) {
        int excl = (b == 0) ? 0 : sc[b - 1];        // exclusive local prefix
        lcur[b]  = excl;
        gbase[b] = off[b * NCHUNK + c] + boff2[b >> 1] - excl;
    }
    __syncthreads();
    int lo = c * CHUNK_E, hi = lo + CHUNK_E; if (hi > ETOT) hi = ETOT;
    int n = hi - lo;
    for (int e = lo + t; e < hi; e += 1024) {
        int s, d; edge_sd(e, ei, s, d);
        int b = d >> 6;
        int slot = atomicAdd(&lcur[b], 1);
        plds[slot] = ((d & 63) << 17) | s;          // src < 2^17
        blds[slot] = (unsigned short)b;
    }
    __syncthreads();
    for (int i = t; i < n; i += 1024)
        pairs[gbase[blds[i]] + i] = plds[i];        // coalesced within segments
}

// ---------------- attention-vector precompute ----------------
// cvec layout: [0,1]=c1s  [2,3]=c1d  [4..19]=c2s  [20..35]=c2d (log2e-prescaled)
__global__ void prep(const float* __restrict__ W1, const float* __restrict__ as1,
                     const float* __restrict__ ad1, const float* __restrict__ W2,
                     const float* __restrict__ as2, const float* __restrict__ ad2,
                     float* __restrict__ cvec) {
    int t = threadIdx.x;
    if (t < 2) {
        float s = 0.f, d = 0.f;
        for (int f = 0; f < 16; ++f) { s += W1[t * 16 + f] * as1[f]; d += W1[t * 16 + f] * ad1[f]; }
        cvec[t] = s * LOG2E; cvec[2 + t] = d * LOG2E;
    }
    if (t < 16) {
        float s = 0.f, d = 0.f;
        for (int f = 0; f < 64; ++f) { s += W2[t * 64 + f] * as2[f]; d += W2[t * 64 + f] * ad2[f]; }
        cvec[4 + t] = s * LOG2E; cvec[20 + t] = d * LOG2E;
    }
}

// Layer-1 node record (16B, one line per edge gather): {x0, x1, as1, pad}.
__global__ void alpha1(const float* __restrict__ x, const float* __restrict__ cvec,
                       float4* __restrict__ nrec1, float* __restrict__ ad_) {
    int n = blockIdx.x * blockDim.x + threadIdx.x;
    if (n >= NNODES) return;
    float2 xv = ((const float2*)x)[n];
    float as = xv.x * cvec[0] + xv.y * cvec[1];
    ad_[n] = xv.x * cvec[2] + xv.y * cvec[3];
    nrec1[n] = make_float4(xv.x, xv.y, as, 0.f);
}

// ---------------- fused fine sort + layer-1 aggregation -----------------------
// Round-30: agg_l1 FUSED into fine_sort2. The block just built this bucket's
// node-compacted edge list — agg_l1 was re-reading it from global (13.2MB) a
// launch later. Now the scatter also fills spc[] in LDS and the same block
// runs the proven round-28 agg_l1 (2 nodes/wave, 32-lane halves, identical
// reduction tree -> bitwise-identical output) over its 64 nodes in 4 passes.
// LDS ~33KB @ 512 threads -> 2-3 blocks/CU. Fallback (n > FS_CAP, >30 sigma
// improbable) reads csr_src back via threadfence.
__global__ __launch_bounds__(512)
void fine_agg1(const int* __restrict__ off, const int* __restrict__ boff2,
               const int* __restrict__ pairs,
               const float4* __restrict__ nrec1, const float* __restrict__ ad_,
               const float* __restrict__ W1, const float* __restrict__ b1,
               const float* __restrict__ cvec,
               int* __restrict__ row_start, int* __restrict__ csr_src,
               float* __restrict__ nrec2, float* __restrict__ ad2_) {
    __shared__ int sp[FS_CAP];               // 16KB arrival-order pairs
    __shared__ int spc[FS_CAP];              // 16KB node-compacted src ids
    __shared__ int arr[NPB];
    __shared__ int cur[NPB];
    __shared__ int lstart[NPB + 1];
    int b = blockIdx.x;
    int t = threadIdx.x;
    int base = off[b * NCHUNK] + boff2[b >> 1];
    int bend = (b == NBUCK - 1) ? ETOT : off[(b + 1) * NCHUNK] + boff2[(b + 1) >> 1];
    int n = bend - base;
    if (t < NPB) arr[t] = 0;
    __syncthreads();
    bool fits = (n <= FS_CAP);
    if (fits) {
        for (int i = t; i < n; i += 512) {
            int p = pairs[base + i];
            sp[i] = p;
            atomicAdd(&arr[p >> 17], 1);
        }
    } else {
        for (int i = t; i < n; i += 512)
            atomicAdd(&arr[pairs[base + i] >> 17], 1);
    }
    __syncthreads();
    int v = (t < NPB) ? arr[t] : 0;
    __syncthreads();
    for (int o = 1; o < NPB; o <<= 1) {           // inclusive scan over 64 counts
        int u = (t < NPB && t >= o) ? arr[t - o] : 0;
        __syncthreads();
        if (t < NPB) arr[t] += u;
        __syncthreads();
    }
    if (t < NPB) {
        int node = b * NPB + t;
        int start = base + arr[t] - v;            // exclusive prefix
        cur[t] = start;
        lstart[t] = start;
        if (node < NNODES) row_start[node] = start;
    }
    if (t == 0) lstart[NPB] = bend;
    if (b == NBUCK - 1 && t == 0) row_start[NNODES] = ETOT;
    __syncthreads();
    if (fits) {
        for (int i = t; i < n; i += 512) {
            int p = sp[i];
            int slot = atomicAdd(&cur[p >> 17], 1);
            int src = p & 0x1FFFF;
            csr_src[slot] = src;
            spc[slot - base] = src;               // LDS copy for fused agg
        }
    } else {
        for (int i = t; i < n; i += 512) {
            int p = pairs[base + i];
            int slot = atomicAdd(&cur[p >> 17], 1);
            csr_src[slot] = p & 0x1FFFF;
        }
        __threadfence_block();
    }
    __syncthreads();
    // ---- fused agg_l1: 8 waves x 2 halves = 16 nodes per pass, 4 passes ----
    int wave = t >> 6;
    int half = (t >> 5) & 1;
    int hlane = t & 31;
#pragma unroll
    for (int pass = 0; pass < 4; ++pass) {
        int ln = pass * 16 + wave * 2 + half;     // 0..63, uniform per half
        int node = b * NPB + ln;
        if (node >= NNODES) continue;             // uniform branch per 32-lane half
        int nbase = lstart[ln], nend = lstart[ln + 1];
        float adv = ad_[node];
        float a0 = 0.f, a1 = 0.f, ss = 0.f;
        if (fits) {
            for (int i = nbase + hlane; i < nend; i += 32) {
                int sj = spc[i - base];
                float4 r = nrec1[sj];             // ONE 16B gather: x0,x1,as1
                float w = edge_w(r.z + adv);
                ss += w; a0 += w * r.x; a1 += w * r.y;
            }
        } else {
            for (int i = nbase + hlane; i < nend; i += 32) {
                int sj = csr_src[i];
                float4 r = nrec1[sj];
                float w = edge_w(r.z + adv);
                ss += w; a0 += w * r.x; a1 += w * r.y;
            }
        }
        a0 = half32_sum(a0); a1 = half32_sum(a1); ss = half32_sum(ss);
        int f = hlane & 15;                       // both rows compute feature f
        float vv = (a0 * W1[f] + a1 * W1[16 + f]) / ss + b1[f];
        float vr = vv > 0.f ? vv : 0.f;
        unsigned short* grow = (unsigned short*)(nrec2 + (size_t)node * 16);
        if (hlane < 16) grow[hlane] = f2bf(vr);   // bf16 g row, bytes 0..31
        // fused alpha2 (f32): row-local 16-feature sums
        float s2 = vr * cvec[4 + f];
        float d2 = vr * cvec[20 + f];
        s2 = row16_sum(s2); d2 = row16_sum(d2);
        if (hlane == 0) {
            nrec2[(size_t)node * 16 + 8] = s2;    // as2 at bytes 32..35 (same line)
            ad2_[node] = d2;
        }
    }
}

// ---------------- layer 2: aggregate bf16 g, @W2 in epilogue ------------------
// Two nodes per wave, 32 lanes each (round-28); one 64B record line per edge
// (round-27); transposed butterfly reduce (round-25), all 32-lane-local;
// per-half totals bounce through wave-local LDS (in-order DS, no barrier).
__global__ void agg_l2(const int* __restrict__ row_start, const int* __restrict__ csr_src,
                       const float* __restrict__ nrec2, const float* __restrict__ ad_,
                       const float* __restrict__ W2, const float* __restrict__ b2,
                       float* __restrict__ out) {
    __shared__ float tot[4][2][16];
    int wave = threadIdx.x >> 6;
    int half = (threadIdx.x >> 5) & 1;
    int hlane = threadIdx.x & 31;
    int node = blockIdx.x * 8 + wave * 2 + half;   // exact grid: NNODES/8 blocks
    int base = row_start[node], end = row_start[node + 1];
    float adv = ad_[node];
    float acc[16];
#pragma unroll
    for (int k = 0; k < 16; ++k) acc[k] = 0.f;
    float ss = 0.f;
    for (int i = base + hlane; i < end; i += 32) {
        int sj = csr_src[i];                        // coalesced (consecutive i)
        const float* recf = nrec2 + (size_t)sj * 16;
        const uint4* rec4 = (const uint4*)recf;
        uint4 u0 = rec4[0], u1 = rec4[1];           // g row bf16x16 (32B)
        float as2v = recf[8];                       // as2 (same 64B line)
        float w = edge_w(as2v + adv);
        ss += w;
        unsigned uu[8] = {u0.x, u0.y, u0.z, u0.w, u1.x, u1.y, u1.z, u1.w};
#pragma unroll
        for (int j = 0; j < 8; ++j) {
            acc[2 * j]     += w * __uint_as_float(uu[j] << 16);
            acc[2 * j + 1] += w * __uint_as_float(uu[j] & 0xFFFF0000u);
        }
    }
    // ---- transposed butterfly (within 16-lane rows): lane l -> feature l&15
#pragma unroll
    for (int j = 0; j < 8; ++j) {
        float keep = (hlane & 1) ? acc[2 * j + 1] : acc[2 * j];
        float send = (hlane & 1) ? acc[2 * j]     : acc[2 * j + 1];
        acc[j] = keep + dpp_mov<0xB1>(send);
    }
#pragma unroll
    for (int j = 0; j < 4; ++j) {
        float keep = (hlane & 2) ? acc[2 * j + 1] : acc[2 * j];
        float send = (hlane & 2) ? acc[2 * j]     : acc[2 * j + 1];
        acc[j] = keep + dpp_mov<0x4E>(send);
    }
#pragma unroll
    for (int j = 0; j < 2; ++j) {
        float keep = (hlane & 4) ? acc[2 * j + 1] : acc[2 * j];
        float send = (hlane & 4) ? acc[2 * j]     : acc[2 * j + 1];
        acc[j] = keep + swz<0x101F>(send);
    }
    float r;
    {
        float keep = (hlane & 8) ? acc[1] : acc[0];
        float send = (hlane & 8) ? acc[0] : acc[1];
        r = keep + swz<0x201F>(send);
    }
    // combine this half's two rows: xor16 (32-lane-local) -> per-node totals
    r = swz16_add(r);
    float st = half32_sum(ss);
    // Totals live in lanes 0..15 (dup 16..31): bounce through wave-local LDS.
    if (hlane < 16) tot[wave][half][hlane] = r;
    float o0 = 0.f, o1 = 0.f;
#pragma unroll
    for (int k = 0; k < 16; ++k) {
        float t = tot[wave][half][k];
        o0 += t * W2[k * 64 + hlane];               // coalesced W2 columns
        o1 += t * W2[k * 64 + 32 + hlane];
    }
    float inv = 1.0f / st;
    o0 = o0 * inv + b2[hlane];
    o1 = o1 * inv + b2[32 + hlane];
    out[(size_t)node * 64 + hlane]      = o0 > 0.f ? o0 : 0.f;
    out[(size_t)node * 64 + 32 + hlane] = o1 > 0.f ? o1 : 0.f;
}

extern "C" void kernel_launch(void* const* d_in, const int* in_sizes, int n_in,
                              void* d_out, int out_size, void* d_ws, size_t ws_size,
                              hipStream_t stream) {
    const float* x     = (const float*)d_in[0];
    const int*   ei    = (const int*)  d_in[1];
    const float* W1    = (const float*)d_in[2];
    const float* as1w  = (const float*)d_in[3];
    const float* ad1w  = (const float*)d_in[4];
    const float* b1    = (const float*)d_in[5];
    const float* W2    = (const float*)d_in[6];
    const float* as2w  = (const float*)d_in[7];
    const float* ad2w  = (const float*)d_in[8];
    const float* b2    = (const float*)d_in[9];
    float* out = (float*)d_out;

    // ws layout (4-byte elems, ~38.8 MB; 40.4 MB proven available):
    //   row_start[N+4] | csr_src[ETOT] | nrec2[N*16 f32 slots = 64B/node] |
    //   adb[N] | ad2b[N] | cvec[64] | pairs[ETOT] | H[M2] | off[M2] |
    //   bsum2[1024] | boff2[1024] | nrec1[N float4]
    int* row_start = (int*)d_ws;
    int* csr_src   = row_start + (NNODES + 4);
    float* nrec2   = (float*)(csr_src + ETOT);   // N*64B: g bf16[16] + as2 + pad
    float* adb     = nrec2 + (size_t)NNODES * 16;
    float* ad2b    = adb + NNODES;
    float* cvec    = ad2b + NNODES;              // 36 floats used
    int* pairs     = (int*)(cvec + 64);          // ETOT
    int* H         = pairs + ETOT;               // M2
    int* off       = H + M2;                     // M2
    int* bsum2     = off + M2;                   // 1024
    int* boff2     = bsum2 + 1024;               // 1024
    float4* nrec1  = (float4*)(boff2 + 1024);    // N*16B: {x0,x1,as1,pad}

    const int B = 256;
    const int NB = (NNODES + B - 1) / B;

    // ---- CSR build: deterministic chunked bucket sort ----
    chunk_hist<<<NCHUNK, 1024, 0, stream>>>(ei, H);
    cscan_local<<<NSB2, 512, 0, stream>>>(H, off, bsum2);
    cscan_bsum<<<1, 1024, 0, stream>>>(bsum2, boff2);
    chunk_scatter<<<NCHUNK, 1024, 0, stream>>>(ei, off, boff2, H, pairs);

    // ---- attention precompute (must precede fine_agg1) ----
    prep<<<1, 64, 0, stream>>>(W1, as1w, ad1w, W2, as2w, ad2w, cvec);
    alpha1<<<NB, B, 0, stream>>>(x, cvec, nrec1, adb);

    // ---- fused fine sort + layer-1 aggregation (agg_l1 kernel eliminated) ----
    fine_agg1<<<NBUCK, 512, 0, stream>>>(off, boff2, pairs, nrec1, adb, W1, b1,
                                         cvec, row_start, csr_src, nrec2, ad2b);

    // ---- Layer 2: aggregate packed records, W2 in epilogue ----
    agg_l2<<<NNODES / 8, B, 0, stream>>>(row_start, csr_src, nrec2, ad2b, W2, b2, out);
}